// Round 9
// baseline (935.359 us; speedup 1.0000x reference)
//
#include <hip/hip_runtime.h>
#include <math.h>

#define B 2048
#define M 65536
#define H 128
#define TDIM 128
#define IDIM 256
#define SC 32            // stats-1 chunks over M
#define SCALE2 0.08838834764831845f
#define PST 36           // padded P-tile row stride (us units)

typedef short bf8 __attribute__((ext_vector_type(8)));
typedef float f32x4 __attribute__((ext_vector_type(4)));
#define MFMA __builtin_amdgcn_mfma_f32_16x16x32_bf16
typedef unsigned short us;

#define SBAR() do { __builtin_amdgcn_sched_barrier(0); \
                    __builtin_amdgcn_s_barrier(); \
                    __builtin_amdgcn_sched_barrier(0); } while (0)
#define VMWAIT0() do { asm volatile("s_waitcnt vmcnt(0)" ::: "memory"); \
                       __builtin_amdgcn_sched_barrier(0); } while (0)
#define SCHED_FENCE() __builtin_amdgcn_sched_barrier(0)

__device__ inline us f2bf(float x) {
    unsigned u = __float_as_uint(x);
    u += 0x7FFF + ((u >> 16) & 1);
    return (us)(u >> 16);
}
__device__ inline float bf2f(us h) { return __uint_as_float(((unsigned)h) << 16); }
__device__ inline void split2(float x, us* hi, us* lo) {
    us h = f2bf(x); *hi = h; *lo = f2bf(x - bf2f(h));
}
__device__ inline bf8 ldb(const us* p) { return *(const bf8*)p; }
__device__ inline void gload16(const void* g, void* l) {
    __builtin_amdgcn_global_load_lds(
        (const __attribute__((address_space(1))) unsigned int*)g,
        (__attribute__((address_space(3))) unsigned int*)l, 16, 0, 0);
}

// ---------------- K1: prep: qt = ((cos-enc)@Wq^T)@Wk -> bf16 hi/lo; vh fp32 --
__global__ __launch_bounds__(128) void k_prep(const float* __restrict__ ts,
        const float* __restrict__ inp, const float* __restrict__ w_t,
        const float* __restrict__ b_t, const float* __restrict__ Wq,
        const float* __restrict__ Wk, const float* __restrict__ Wv,
        us* __restrict__ qt_hi, us* __restrict__ qt_lo, float* __restrict__ vh) {
    __shared__ float temb[TDIM];
    __shared__ float qh[H];
    const int b = blockIdx.x, t = threadIdx.x;
    temb[t] = cosf(ts[b] * w_t[t] + b_t[t]);
    __syncthreads();
    float s = 0.f;
    for (int k = 0; k < TDIM; k++) s += temb[k] * Wq[t * TDIM + k];
    qh[t] = s;
    __syncthreads();
    float s2 = 0.f;
    for (int j = 0; j < H; j++) s2 += qh[j] * Wk[j * H + t];
    us h, l;
    split2(s2, &h, &l);
    qt_hi[b * H + t] = h; qt_lo[b * H + t] = l;
    float s3 = 0.f;
    for (int i = 0; i < IDIM; i++) s3 += inp[b * IDIM + i] * Wv[t * IDIM + i];
    vh[b * H + t] = s3;
}

// ---------------- K2: split memory -> bf16 hi/lo -----------------------------
__global__ __launch_bounds__(256) void k_splitmem(const float* __restrict__ x,
        us* __restrict__ hi, us* __restrict__ lo, int n) {
    int i = blockIdx.x * 256 + threadIdx.x;
    const int stride = gridDim.x * 256;
    for (; i < n; i += stride) {
        us h, l;
        split2(x[i], &h, &l);
        hi[i] = h; lo[i] = l;
    }
}

// ---------------- K3: vh [B][H] -> vhT_hi [H][B] (hi only) -------------------
__global__ __launch_bounds__(256) void k_tx(const float* __restrict__ vh,
        us* __restrict__ vhT_hi) {
    const int d = blockIdx.x;
    const int b = blockIdx.y * 256 + threadIdx.x;
    vhT_hi[d * B + b] = f2bf(vh[b * H + d]);
}

// ---------------- K4: stats pass 1 (deferred-max sumexp over m) --------------
// One barrier/iter: {vmcnt0; bar; STAGE(t+1); QK; softmax}.
__global__ __launch_bounds__(256) void k_stats(const us* __restrict__ src_hi,
        const us* __restrict__ src_lo,
        const us* __restrict__ qt_hi, const us* __restrict__ qt_lo,
        int mchunk, float* __restrict__ pmax, float* __restrict__ psum) {
    __shared__ us lds[16384];
    const int tid = threadIdx.x;
    const int w = tid >> 6, l = tid & 63;
    const int lr = l & 15, g = l >> 4;
    const int brow = blockIdx.x * 128 + w * 32;
    const int m0b = blockIdx.y * mchunk;
    const int rq = l >> 4, cq = l & 15;
    bf8 qh[2][4], ql[2][4];
#pragma unroll
    for (int bt = 0; bt < 2; bt++)
#pragma unroll
        for (int kk = 0; kk < 4; kk++) {
            const int o = (brow + bt * 16 + lr) * H + kk * 32 + g * 8;
            qh[bt][kk] = ldb(qt_hi + o);
            ql[bt][kk] = ldb(qt_lo + o);
        }
    float mb[8], sm[8];
#pragma unroll
    for (int i = 0; i < 8; i++) { mb[i] = -INFINITY; sm[i] = 0.f; }
    auto STAGE = [&](int t, int bi) {
        const int m0 = m0b + t * 32;
        us* Q = lds + bi * 8192;
#pragma unroll
        for (int i = 0; i < 4; i++) {
            const int id = w * 4 + i;
            const int ii = id & 7;
            const int r = ii * 4 + rq;
            const int cc = cq ^ (r & 7);
            gload16((id < 8 ? src_hi : src_lo) + (size_t)(m0 + r) * H + cc * 8,
                    Q + (id < 8 ? 0 : 4096) + ii * 512);
        }
    };
    STAGE(0, 0);
    int cur = 0;
    const int NT = mchunk / 32;
    for (int t = 0; t < NT; t++) {
        VMWAIT0();
        SBAR();   // tile t landed for all waves; prev reads of buf[cur^1] done
        if (t + 1 < NT) STAGE(t + 1, cur ^ 1);
        SCHED_FENCE();
        const us* Q = lds + cur * 8192;
        f32x4 c[2][2];
#pragma unroll
        for (int bt = 0; bt < 2; bt++)
#pragma unroll
            for (int mt = 0; mt < 2; mt++) c[bt][mt] = (f32x4){0.f, 0.f, 0.f, 0.f};
        __builtin_amdgcn_s_setprio(1);
#pragma unroll
        for (int kk = 0; kk < 4; kk++) {
            const int co = ((kk * 4 + g) ^ (lr & 7)) * 8;
            bf8 b0h = *(const bf8*)(Q + lr * 128 + co);
            bf8 b0l = *(const bf8*)(Q + 4096 + lr * 128 + co);
            bf8 b1h = *(const bf8*)(Q + (16 + lr) * 128 + co);
            bf8 b1l = *(const bf8*)(Q + 4096 + (16 + lr) * 128 + co);
            c[0][0] = MFMA(qh[0][kk], b0h, c[0][0], 0, 0, 0);
            c[0][0] = MFMA(ql[0][kk], b0h, c[0][0], 0, 0, 0);
            c[0][0] = MFMA(qh[0][kk], b0l, c[0][0], 0, 0, 0);
            c[0][1] = MFMA(qh[0][kk], b1h, c[0][1], 0, 0, 0);
            c[0][1] = MFMA(ql[0][kk], b1h, c[0][1], 0, 0, 0);
            c[0][1] = MFMA(qh[0][kk], b1l, c[0][1], 0, 0, 0);
            c[1][0] = MFMA(qh[1][kk], b0h, c[1][0], 0, 0, 0);
            c[1][0] = MFMA(ql[1][kk], b0h, c[1][0], 0, 0, 0);
            c[1][0] = MFMA(qh[1][kk], b0l, c[1][0], 0, 0, 0);
            c[1][1] = MFMA(qh[1][kk], b1h, c[1][1], 0, 0, 0);
            c[1][1] = MFMA(ql[1][kk], b1h, c[1][1], 0, 0, 0);
            c[1][1] = MFMA(qh[1][kk], b1l, c[1][1], 0, 0, 0);
        }
        __builtin_amdgcn_s_setprio(0);
        float dm = -INFINITY;
#pragma unroll
        for (int bt = 0; bt < 2; bt++)
#pragma unroll
            for (int mt = 0; mt < 2; mt++)
#pragma unroll
                for (int r = 0; r < 4; r++)
                    dm = fmaxf(dm, c[bt][mt][r] - mb[bt * 4 + r]);
        if (__any(dm > 8.f)) {
#pragma unroll
            for (int bt = 0; bt < 2; bt++)
#pragma unroll
                for (int r = 0; r < 4; r++) {
                    const int s = bt * 4 + r;
                    float mx = fmaxf(mb[s], fmaxf(c[bt][0][r], c[bt][1][r]));
                    sm[s] = sm[s] * __expf(mb[s] - mx)
                          + __expf(c[bt][0][r] - mx) + __expf(c[bt][1][r] - mx);
                    mb[s] = mx;
                }
        } else {
#pragma unroll
            for (int bt = 0; bt < 2; bt++)
#pragma unroll
                for (int r = 0; r < 4; r++) {
                    const int s = bt * 4 + r;
                    sm[s] += __expf(c[bt][0][r] - mb[s]) + __expf(c[bt][1][r] - mb[s]);
                }
        }
        cur ^= 1;
    }
#pragma unroll
    for (int s = 0; s < 8; s++) {
#pragma unroll
        for (int x = 1; x < 16; x <<= 1) {
            float om = __shfl_xor(mb[s], x);
            float os = __shfl_xor(sm[s], x);
            float nm = fmaxf(mb[s], om);
            sm[s] = sm[s] * __expf(mb[s] - nm) + os * __expf(om - nm);
            mb[s] = nm;
        }
    }
    if (lr == 0) {
#pragma unroll
        for (int bt = 0; bt < 2; bt++)
#pragma unroll
            for (int r = 0; r < 4; r++) {
                const int row = brow + bt * 16 + g * 4 + r;
                pmax[row * SC + blockIdx.y] = mb[bt * 4 + r];
                psum[row * SC + blockIdx.y] = sm[bt * 4 + r];
            }
    }
}

// ---------------- K5: combine -> ffac[b] = exp(-gmax)/Z ----------------------
__global__ __launch_bounds__(256) void k_combine1(const float* __restrict__ pmax,
        const float* __restrict__ psum, float* __restrict__ ffac) {
    const int b = blockIdx.x * 256 + threadIdx.x;
    float mx = -INFINITY;
    for (int c = 0; c < SC; c++) mx = fmaxf(mx, pmax[b * SC + c]);
    float z = 0.f;
    for (int c = 0; c < SC; c++) z += psum[b * SC + c] * __expf(pmax[b * SC + c] - mx);
    ffac[b] = __expf(-mx) / z;
}

// ---------------- K6: update: memw = normalize(memory + P1^T @ vh) -----------
// One barrier/iter; V tile in per-wave registers (dwordx4, QK covers latency).
__global__ __launch_bounds__(256) void k_update(const float* __restrict__ memory,
        const us* __restrict__ mem_hi, const us* __restrict__ mem_lo,
        const us* __restrict__ qt_hi, const us* __restrict__ qt_lo,
        const us* __restrict__ vhT_hi, const float* __restrict__ ffac,
        us* __restrict__ memw_hi, us* __restrict__ memw_lo,
        us* __restrict__ memwT_hi) {
    __shared__ us lds[25600]; // qt dbuf 2x8192 | P 4x2304; epilogue reuses [0,17408)
    const int tid = threadIdx.x;
    const int w = tid >> 6, l = tid & 63;
    const int lr = l & 15, g = l >> 4;
    const int mrow = blockIdx.x * 128 + w * 32;
    const int rq = l >> 4, cq = l & 15;
    bf8 bh[2][4], bl[2][4];
#pragma unroll
    for (int t = 0; t < 2; t++)
#pragma unroll
        for (int kk = 0; kk < 4; kk++) {
            const int o = (mrow + t * 16 + lr) * H + kk * 32 + g * 8;
            bh[t][kk] = ldb(mem_hi + o);
            bl[t][kk] = ldb(mem_lo + o);
        }
    f32x4 acc[2][8];
#pragma unroll
    for (int t = 0; t < 2; t++)
#pragma unroll
        for (int dt = 0; dt < 8; dt++) acc[t][dt] = (f32x4){0.f, 0.f, 0.f, 0.f};
    us* Ph = lds + 16384 + w * 2304;
    us* Pl = Ph + 1152;
    auto STAGE_QT = [&](int t, int bi) {
        const int b0 = t * 32;
        us* Q = lds + bi * 8192;
#pragma unroll
        for (int i = 0; i < 4; i++) {
            const int id = w * 4 + i;
            const int ii = id & 7;
            const int r = ii * 4 + rq;
            const int cc = cq ^ (r & 7);
            gload16((id < 8 ? qt_hi : qt_lo) + (size_t)(b0 + r) * H + cc * 8,
                    Q + (id < 8 ? 0 : 4096) + ii * 512);
        }
    };
    STAGE_QT(0, 0);
    int cur = 0;
    const int NT = B / 32;
    for (int t = 0; t < NT; t++) {
        VMWAIT0();
        SBAR();   // Q(t) landed; prev reads of buf[cur^1] done
        const int b0 = t * 32;
        // V(t) reg loads FIRST so the compiler's pre-PV wait keeps Q(t+1) in flight
        bf8 vreg[8];
#pragma unroll
        for (int dt = 0; dt < 8; dt++)
            vreg[dt] = ldb(vhT_hi + (size_t)(dt * 16 + lr) * B + b0 + g * 8);
        SCHED_FENCE();
        if (t + 1 < NT) STAGE_QT(t + 1, cur ^ 1);
        SCHED_FENCE();
        const us* Q = lds + cur * 8192;
        f32x4 c[2][2];
#pragma unroll
        for (int bt = 0; bt < 2; bt++)
#pragma unroll
            for (int mt = 0; mt < 2; mt++) c[bt][mt] = (f32x4){0.f, 0.f, 0.f, 0.f};
        __builtin_amdgcn_s_setprio(1);
#pragma unroll
        for (int kk = 0; kk < 4; kk++) {
            const int co = ((kk * 4 + g) ^ (lr & 7)) * 8;
            bf8 a0h = *(const bf8*)(Q + lr * 128 + co);
            bf8 a0l = *(const bf8*)(Q + 4096 + lr * 128 + co);
            bf8 a1h = *(const bf8*)(Q + (16 + lr) * 128 + co);
            bf8 a1l = *(const bf8*)(Q + 4096 + (16 + lr) * 128 + co);
            c[0][0] = MFMA(a0h, bh[0][kk], c[0][0], 0, 0, 0);
            c[0][0] = MFMA(a0l, bh[0][kk], c[0][0], 0, 0, 0);
            c[0][0] = MFMA(a0h, bl[0][kk], c[0][0], 0, 0, 0);
            c[0][1] = MFMA(a0h, bh[1][kk], c[0][1], 0, 0, 0);
            c[0][1] = MFMA(a0l, bh[1][kk], c[0][1], 0, 0, 0);
            c[0][1] = MFMA(a0h, bl[1][kk], c[0][1], 0, 0, 0);
            c[1][0] = MFMA(a1h, bh[0][kk], c[1][0], 0, 0, 0);
            c[1][0] = MFMA(a1l, bh[0][kk], c[1][0], 0, 0, 0);
            c[1][0] = MFMA(a1h, bl[0][kk], c[1][0], 0, 0, 0);
            c[1][1] = MFMA(a1h, bh[1][kk], c[1][1], 0, 0, 0);
            c[1][1] = MFMA(a1l, bh[1][kk], c[1][1], 0, 0, 0);
            c[1][1] = MFMA(a1h, bl[1][kk], c[1][1], 0, 0, 0);
        }
        __builtin_amdgcn_s_setprio(0);
        const float4 f4a = *(const float4*)(ffac + b0 + g * 4);
        const float4 f4b = *(const float4*)(ffac + b0 + 16 + g * 4);
        float fa[4] = {f4a.x, f4a.y, f4a.z, f4a.w};
        float fb[4] = {f4b.x, f4b.y, f4b.z, f4b.w};
#pragma unroll
        for (int bt = 0; bt < 2; bt++) {
#pragma unroll
            for (int mt = 0; mt < 2; mt++) {
                us hh[4], ll[4];
#pragma unroll
                for (int r = 0; r < 4; r++) {
                    float p = __expf(c[bt][mt][r]) * (bt ? fb[r] : fa[r]);
                    split2(p, &hh[r], &ll[r]);
                }
                uint2 v;
                v.x = (unsigned)hh[0] | ((unsigned)hh[1] << 16);
                v.y = (unsigned)hh[2] | ((unsigned)hh[3] << 16);
                *(uint2*)(Ph + (mt * 16 + lr) * PST + bt * 16 + g * 4) = v;
                v.x = (unsigned)ll[0] | ((unsigned)ll[1] << 16);
                v.y = (unsigned)ll[2] | ((unsigned)ll[3] << 16);
                *(uint2*)(Pl + (mt * 16 + lr) * PST + bt * 16 + g * 4) = v;
            }
        }
        bf8 pah[2], pal[2];
#pragma unroll
        for (int mt = 0; mt < 2; mt++) {
            pah[mt] = *(const bf8*)(Ph + (mt * 16 + lr) * PST + g * 8);
            pal[mt] = *(const bf8*)(Pl + (mt * 16 + lr) * PST + g * 8);
        }
        __builtin_amdgcn_s_setprio(1);
#pragma unroll
        for (int dt = 0; dt < 8; dt++) {
            acc[0][dt] = MFMA(pah[0], vreg[dt], acc[0][dt], 0, 0, 0);
            acc[0][dt] = MFMA(pal[0], vreg[dt], acc[0][dt], 0, 0, 0);
            acc[1][dt] = MFMA(pah[1], vreg[dt], acc[1][dt], 0, 0, 0);
            acc[1][dt] = MFMA(pal[1], vreg[dt], acc[1][dt], 0, 0, 0);
        }
        __builtin_amdgcn_s_setprio(0);
        cur ^= 1;
    }
    // epilogue: new = memory + acc; L2-normalize; write memw_hi/lo + memwT_hi
    float n2[2][4];
#pragma unroll
    for (int t = 0; t < 2; t++)
#pragma unroll
        for (int r = 0; r < 4; r++) n2[t][r] = 0.f;
#pragma unroll
    for (int t = 0; t < 2; t++)
#pragma unroll
        for (int dt = 0; dt < 8; dt++)
#pragma unroll
            for (int r = 0; r < 4; r++) {
                float v = acc[t][dt][r]
                        + memory[(mrow + t * 16 + g * 4 + r) * H + dt * 16 + lr];
                acc[t][dt][r] = v;
                n2[t][r] += v * v;
            }
#pragma unroll
    for (int t = 0; t < 2; t++)
#pragma unroll
        for (int r = 0; r < 4; r++) {
#pragma unroll
            for (int x = 1; x < 16; x <<= 1) n2[t][r] += __shfl_xor(n2[t][r], x);
            n2[t][r] = 1.f / fmaxf(sqrtf(n2[t][r]), 1e-12f);
        }
#pragma unroll
    for (int t = 0; t < 2; t++)
#pragma unroll
        for (int dt = 0; dt < 8; dt++)
#pragma unroll
            for (int r = 0; r < 4; r++) {
                float vv = acc[t][dt][r] * n2[t][r];
                us h = f2bf(vv);
                memw_hi[(mrow + t * 16 + g * 4 + r) * H + dt * 16 + lr] = h;
                memw_lo[(mrow + t * 16 + g * 4 + r) * H + dt * 16 + lr]
                    = f2bf(vv - bf2f(h));
            }
    __syncthreads();
#pragma unroll
    for (int t = 0; t < 2; t++)
#pragma unroll
        for (int dt = 0; dt < 8; dt++)
#pragma unroll
            for (int r = 0; r < 4; r++) {
                float vv = acc[t][dt][r] * n2[t][r];
                lds[(dt * 16 + lr) * 136 + w * 32 + t * 16 + g * 4 + r] = f2bf(vv);
            }
    __syncthreads();
    {
        const int d = tid >> 1, seg = tid & 1;
        uint4* dq = (uint4*)(memwT_hi + (size_t)d * M + blockIdx.x * 128 + seg * 64);
        const uint4* sp = (const uint4*)(lds + d * 136 + seg * 64);
#pragma unroll
        for (int j = 0; j < 8; j++) dq[j] = sp[j];
    }
}

// ---------------- K7: flash read: fused stats2 + PV over m-chunks ------------
// Same one-barrier schedule; memwT tile in per-wave registers.
__global__ __launch_bounds__(256) void k_fread(const us* __restrict__ memw_hi,
        const us* __restrict__ memw_lo, const us* __restrict__ memwT_hi,
        const us* __restrict__ qt_hi, const us* __restrict__ qt_lo,
        float* __restrict__ part, float* __restrict__ pmax2,
        float* __restrict__ psum2, int mchunk) {
    __shared__ us lds[25600];
    const int tid = threadIdx.x;
    const int w = tid >> 6, l = tid & 63;
    const int lr = l & 15, g = l >> 4;
    const int brow = blockIdx.x * 128 + w * 32;
    const int m0b = blockIdx.y * mchunk;
    const int rq = l >> 4, cq = l & 15;
    bf8 qh[2][4], ql[2][4];
#pragma unroll
    for (int bt = 0; bt < 2; bt++)
#pragma unroll
        for (int kk = 0; kk < 4; kk++) {
            const int o = (brow + bt * 16 + lr) * H + kk * 32 + g * 8;
            qh[bt][kk] = ldb(qt_hi + o);
            ql[bt][kk] = ldb(qt_lo + o);
        }
    f32x4 acc[2][8];
#pragma unroll
    for (int bt = 0; bt < 2; bt++)
#pragma unroll
        for (int dt = 0; dt < 8; dt++) acc[bt][dt] = (f32x4){0.f, 0.f, 0.f, 0.f};
    float mb0 = 0.f, sm0 = 0.f, mb1 = 0.f, sm1 = 0.f;
    us* Ph = lds + 16384 + w * 2304;
    us* Pl = Ph + 1152;
    auto STAGE_MW = [&](int t, int bi) {
        const int m0 = m0b + t * 32;
        us* Q = lds + bi * 8192;
#pragma unroll
        for (int i = 0; i < 4; i++) {
            const int id = w * 4 + i;
            const int ii = id & 7;
            const int r = ii * 4 + rq;
            const int cc = cq ^ (r & 7);
            gload16((id < 8 ? memw_hi : memw_lo) + (size_t)(m0 + r) * H + cc * 8,
                    Q + (id < 8 ? 0 : 4096) + ii * 512);
        }
    };
    STAGE_MW(0, 0);
    int cur = 0;
    const int NT = mchunk / 32;
    for (int t = 0; t < NT; t++) {
        VMWAIT0();
        SBAR();
        const int m0 = m0b + t * 32;
        bf8 vreg[8];
#pragma unroll
        for (int dt = 0; dt < 8; dt++)
            vreg[dt] = ldb(memwT_hi + (size_t)(dt * 16 + lr) * M + m0 + g * 8);
        SCHED_FENCE();
        if (t + 1 < NT) STAGE_MW(t + 1, cur ^ 1);
        SCHED_FENCE();
        const us* Q = lds + cur * 8192;
        f32x4 c[2][2];
#pragma unroll
        for (int mt = 0; mt < 2; mt++)
#pragma unroll
            for (int bt = 0; bt < 2; bt++) c[mt][bt] = (f32x4){0.f, 0.f, 0.f, 0.f};
        __builtin_amdgcn_s_setprio(1);
#pragma unroll
        for (int kk = 0; kk < 4; kk++) {
            const int co = ((kk * 4 + g) ^ (lr & 7)) * 8;
            bf8 a0h = *(const bf8*)(Q + lr * 128 + co);
            bf8 a0l = *(const bf8*)(Q + 4096 + lr * 128 + co);
            bf8 a1h = *(const bf8*)(Q + (16 + lr) * 128 + co);
            bf8 a1l = *(const bf8*)(Q + 4096 + (16 + lr) * 128 + co);
            c[0][0] = MFMA(a0h, qh[0][kk], c[0][0], 0, 0, 0);
            c[0][0] = MFMA(a0l, qh[0][kk], c[0][0], 0, 0, 0);
            c[0][0] = MFMA(a0h, ql[0][kk], c[0][0], 0, 0, 0);
            c[0][1] = MFMA(a0h, qh[1][kk], c[0][1], 0, 0, 0);
            c[0][1] = MFMA(a0l, qh[1][kk], c[0][1], 0, 0, 0);
            c[0][1] = MFMA(a0h, ql[1][kk], c[0][1], 0, 0, 0);
            c[1][0] = MFMA(a1h, qh[0][kk], c[1][0], 0, 0, 0);
            c[1][0] = MFMA(a1l, qh[0][kk], c[1][0], 0, 0, 0);
            c[1][0] = MFMA(a1h, ql[0][kk], c[1][0], 0, 0, 0);
            c[1][1] = MFMA(a1h, qh[1][kk], c[1][1], 0, 0, 0);
            c[1][1] = MFMA(a1l, qh[1][kk], c[1][1], 0, 0, 0);
            c[1][1] = MFMA(a1h, ql[1][kk], c[1][1], 0, 0, 0);
        }
        __builtin_amdgcn_s_setprio(0);
        float s[2][2][4];
        float lmax0 = -INFINITY, lmax1 = -INFINITY;
#pragma unroll
        for (int mt = 0; mt < 2; mt++)
#pragma unroll
            for (int r = 0; r < 4; r++) {
                s[mt][0][r] = c[mt][0][r] * SCALE2;
                s[mt][1][r] = c[mt][1][r] * SCALE2;
                lmax0 = fmaxf(lmax0, s[mt][0][r]);
                lmax1 = fmaxf(lmax1, s[mt][1][r]);
            }
        lmax0 = fmaxf(lmax0, __shfl_xor(lmax0, 16));
        lmax0 = fmaxf(lmax0, __shfl_xor(lmax0, 32));
        lmax1 = fmaxf(lmax1, __shfl_xor(lmax1, 16));
        lmax1 = fmaxf(lmax1, __shfl_xor(lmax1, 32));
        if (__any((lmax0 > mb0 + 8.f) || (lmax1 > mb1 + 8.f))) {
            float nm0 = fmaxf(mb0, lmax0), f0 = __expf(mb0 - nm0);
            float nm1 = fmaxf(mb1, lmax1), f1 = __expf(mb1 - nm1);
            sm0 *= f0; sm1 *= f1;
            float fr0[4], fr1[4];
#pragma unroll
            for (int r = 0; r < 4; r++) {
                fr0[r] = __shfl(f0, g * 4 + r);
                fr1[r] = __shfl(f1, g * 4 + r);
            }
#pragma unroll
            for (int dt = 0; dt < 8; dt++)
#pragma unroll
                for (int r = 0; r < 4; r++) {
                    acc[0][dt][r] *= fr0[r];
                    acc[1][dt][r] *= fr1[r];
                }
            mb0 = nm0; mb1 = nm1;
        }
#pragma unroll
        for (int bt = 0; bt < 2; bt++) {
            const float mbx = bt ? mb1 : mb0;
#pragma unroll
            for (int mt = 0; mt < 2; mt++) {
                us hh[4], ll[4];
#pragma unroll
                for (int r = 0; r < 4; r++) {
                    float p = __expf(s[mt][bt][r] - mbx);
                    if (bt) sm1 += p; else sm0 += p;
                    split2(p, &hh[r], &ll[r]);
                }
                uint2 v;
                v.x = (unsigned)hh[0] | ((unsigned)hh[1] << 16);
                v.y = (unsigned)hh[2] | ((unsigned)hh[3] << 16);
                *(uint2*)(Ph + (bt * 16 + lr) * PST + mt * 16 + g * 4) = v;
                v.x = (unsigned)ll[0] | ((unsigned)ll[1] << 16);
                v.y = (unsigned)ll[2] | ((unsigned)ll[3] << 16);
                *(uint2*)(Pl + (bt * 16 + lr) * PST + mt * 16 + g * 4) = v;
            }
        }
        bf8 pah[2], pal[2];
#pragma unroll
        for (int bt = 0; bt < 2; bt++) {
            pah[bt] = *(const bf8*)(Ph + (bt * 16 + lr) * PST + g * 8);
            pal[bt] = *(const bf8*)(Pl + (bt * 16 + lr) * PST + g * 8);
        }
        __builtin_amdgcn_s_setprio(1);
#pragma unroll
        for (int dt = 0; dt < 8; dt++) {
            acc[0][dt] = MFMA(pah[0], vreg[dt], acc[0][dt], 0, 0, 0);
            acc[0][dt] = MFMA(pal[0], vreg[dt], acc[0][dt], 0, 0, 0);
            acc[1][dt] = MFMA(pah[1], vreg[dt], acc[1][dt], 0, 0, 0);
            acc[1][dt] = MFMA(pal[1], vreg[dt], acc[1][dt], 0, 0, 0);
        }
        __builtin_amdgcn_s_setprio(0);
        cur ^= 1;
    }
    sm0 += __shfl_xor(sm0, 16); sm0 += __shfl_xor(sm0, 32);
    sm1 += __shfl_xor(sm1, 16); sm1 += __shfl_xor(sm1, 32);
    if (g == 0) {
        pmax2[(size_t)blockIdx.y * B + brow + lr] = mb0;
        psum2[(size_t)blockIdx.y * B + brow + lr] = sm0;
        pmax2[(size_t)blockIdx.y * B + brow + 16 + lr] = mb1;
        psum2[(size_t)blockIdx.y * B + brow + 16 + lr] = sm1;
    }
    float* rp = part + (size_t)blockIdx.y * B * H;
#pragma unroll
    for (int bt = 0; bt < 2; bt++)
#pragma unroll
        for (int dt = 0; dt < 8; dt++)
#pragma unroll
            for (int r = 0; r < 4; r++)
                rp[(size_t)(brow + bt * 16 + g * 4 + r) * H + dt * 16 + lr] =
                    acc[bt][dt][r];
}

// ---------------- K8: per-b chunk weights ------------------------------------
__global__ __launch_bounds__(256) void k_fstats(const float* __restrict__ pmax2,
        const float* __restrict__ psum2, float* __restrict__ wc, int nc) {
    const int b = blockIdx.x * 256 + threadIdx.x;
    float gm = -INFINITY;
    for (int c = 0; c < nc; c++) gm = fmaxf(gm, pmax2[(size_t)c * B + b]);
    float z = 0.f;
    for (int c = 0; c < nc; c++)
        z += psum2[(size_t)c * B + b] * __expf(pmax2[(size_t)c * B + b] - gm);
    const float zi = 1.f / z;
    for (int c = 0; c < nc; c++)
        wc[(size_t)c * B + b] = __expf(pmax2[(size_t)c * B + b] - gm) * zi;
}

// ---------------- K9: weighted combine -> out --------------------------------
__global__ __launch_bounds__(256) void k_fcombine(const float* __restrict__ part,
        const float* __restrict__ wc, float* __restrict__ out, int nc) {
    const int i = blockIdx.x * 256 + threadIdx.x;
    const int b = i >> 7;
    float s = 0.f;
    for (int c = 0; c < nc; c++) s += part[(size_t)c * B * H + i] * wc[(size_t)c * B + b];
    out[i] = s;
}

extern "C" void kernel_launch(void* const* d_in, const int* in_sizes, int n_in,
                              void* d_out, int out_size, void* d_ws, size_t ws_size,
                              hipStream_t stream) {
    const float* ts     = (const float*)d_in[0];
    const float* inp    = (const float*)d_in[1];
    const float* memory = (const float*)d_in[2];
    const float* w_t    = (const float*)d_in[3];
    const float* b_t    = (const float*)d_in[4];
    const float* Wq     = (const float*)d_in[5];
    const float* Wk     = (const float*)d_in[6];
    const float* Wv     = (const float*)d_in[7];
    float* out = (float*)d_out;

    char* p = (char*)d_ws;
    auto alloc = [&](size_t bytes) { char* r = p; p += (bytes + 255) & ~(size_t)255; return r; };
    us* mem_hi   = (us*)alloc((size_t)M * H * 2);
    us* mem_lo   = (us*)alloc((size_t)M * H * 2);
    us* memw_hi  = (us*)alloc((size_t)M * H * 2);
    us* memw_lo  = (us*)alloc((size_t)M * H * 2);
    us* memwT_hi = (us*)alloc((size_t)M * H * 2);
    us* qt_hi    = (us*)alloc((size_t)B * H * 2);
    us* qt_lo    = (us*)alloc((size_t)B * H * 2);
    us* vhT_hi   = (us*)alloc((size_t)B * H * 2);
    float* vh    = (float*)alloc((size_t)B * H * 4);
    float* pmax  = (float*)alloc((size_t)B * SC * 4);
    float* psum  = (float*)alloc((size_t)B * SC * 4);
    float* ffac  = (float*)alloc((size_t)B * 4);
    size_t remain = ws_size - (size_t)(p - (char*)d_ws);
    int NC = 1;
    for (int c = 32; c >= 1; c >>= 1) {
        size_t need = (size_t)c * B * H * 4 + 3 * (size_t)c * B * 4 + 4096;
        if (need <= remain) { NC = c; break; }
    }
    float* pmax2 = (float*)alloc((size_t)NC * B * 4);
    float* psum2 = (float*)alloc((size_t)NC * B * 4);
    float* wcb   = (float*)alloc((size_t)NC * B * 4);
    float* part  = (float*)alloc((size_t)NC * B * H * 4);
    const int mchunk = M / NC;

    hipLaunchKernelGGL(k_prep, dim3(B), dim3(128), 0, stream,
                       ts, inp, w_t, b_t, Wq, Wk, Wv, qt_hi, qt_lo, vh);
    hipLaunchKernelGGL(k_splitmem, dim3(2048), dim3(256), 0, stream,
                       memory, mem_hi, mem_lo, M * H);
    hipLaunchKernelGGL(k_tx, dim3(H, B / 256), dim3(256), 0, stream, vh, vhT_hi);
    hipLaunchKernelGGL(k_stats, dim3(B / 128, SC), dim3(256), 0, stream,
                       mem_hi, mem_lo, qt_hi, qt_lo, M / SC, pmax, psum);
    hipLaunchKernelGGL(k_combine1, dim3(B / 256), dim3(256), 0, stream, pmax, psum, ffac);
    hipLaunchKernelGGL(k_update, dim3(M / 128), dim3(256), 0, stream,
                       memory, mem_hi, mem_lo, qt_hi, qt_lo, vhT_hi,
                       ffac, memw_hi, memw_lo, memwT_hi);
    hipLaunchKernelGGL(k_fread, dim3(B / 128, NC), dim3(256), 0, stream,
                       memw_hi, memw_lo, memwT_hi, qt_hi, qt_lo,
                       part, pmax2, psum2, mchunk);
    hipLaunchKernelGGL(k_fstats, dim3(B / 256), dim3(256), 0, stream, pmax2, psum2, wcb, NC);
    hipLaunchKernelGGL(k_fcombine, dim3(B * H / 256), dim3(256), 0, stream, part, wcb, out, NC);
}

// Round 10
// 772.829 us; speedup vs baseline: 1.2103x; 1.2103x over previous
//
#include <hip/hip_runtime.h>
#include <math.h>

#define B 2048
#define M 65536
#define H 128
#define TDIM 128
#define IDIM 256
#define SC 32            // stats-1 chunks over M
#define SCALE2 0.08838834764831845f
#define PST 36           // P-tile row stride (us units); slots XOR-swizzled within row

typedef short bf8 __attribute__((ext_vector_type(8)));
typedef float f32x4 __attribute__((ext_vector_type(4)));
#define MFMA __builtin_amdgcn_mfma_f32_16x16x32_bf16
typedef unsigned short us;

// raw barrier + counted vmcnt (T3/T4-lite). sched_barrier pins codegen (rule #18).
#define SBAR() do { __builtin_amdgcn_sched_barrier(0); \
                    __builtin_amdgcn_s_barrier(); \
                    __builtin_amdgcn_sched_barrier(0); } while (0)
#define VMWAIT(N) do { asm volatile("s_waitcnt vmcnt(" #N ")" ::: "memory"); \
                       __builtin_amdgcn_sched_barrier(0); } while (0)

__device__ inline us f2bf(float x) {
    unsigned u = __float_as_uint(x);
    u += 0x7FFF + ((u >> 16) & 1);
    return (us)(u >> 16);
}
__device__ inline float bf2f(us h) { return __uint_as_float(((unsigned)h) << 16); }
__device__ inline void split2(float x, us* hi, us* lo) {
    us h = f2bf(x); *hi = h; *lo = f2bf(x - bf2f(h));
}
// hot-loop split: hi = truncated top bits (1 op); hi+lo preserves x to same total precision
__device__ inline void split2t(float x, us* hi, us* lo) {
    us h = (us)(__float_as_uint(x) >> 16);
    *hi = h; *lo = f2bf(x - bf2f(h));
}
__device__ inline bf8 ldb(const us* p) { return *(const bf8*)p; }
__device__ inline void gload16(const void* g, void* l) {
    __builtin_amdgcn_global_load_lds(
        (const __attribute__((address_space(1))) unsigned int*)g,
        (__attribute__((address_space(3))) unsigned int*)l, 16, 0, 0);
}

// ---------------- K1: prep: qt = ((cos-enc)@Wq^T)@Wk -> bf16 hi/lo; vh fp32 --
__global__ __launch_bounds__(128) void k_prep(const float* __restrict__ ts,
        const float* __restrict__ inp, const float* __restrict__ w_t,
        const float* __restrict__ b_t, const float* __restrict__ Wq,
        const float* __restrict__ Wk, const float* __restrict__ Wv,
        us* __restrict__ qt_hi, us* __restrict__ qt_lo, float* __restrict__ vh) {
    __shared__ float temb[TDIM];
    __shared__ float qh[H];
    const int b = blockIdx.x, t = threadIdx.x;
    temb[t] = cosf(ts[b] * w_t[t] + b_t[t]);
    __syncthreads();
    float s = 0.f;
    for (int k = 0; k < TDIM; k++) s += temb[k] * Wq[t * TDIM + k];
    qh[t] = s;
    __syncthreads();
    float s2 = 0.f;
    for (int j = 0; j < H; j++) s2 += qh[j] * Wk[j * H + t];
    us h, l;
    split2(s2, &h, &l);
    qt_hi[b * H + t] = h; qt_lo[b * H + t] = l;
    float s3 = 0.f;
    for (int i = 0; i < IDIM; i++) s3 += inp[b * IDIM + i] * Wv[t * IDIM + i];
    vh[b * H + t] = s3;
}

// ---------------- K2: split memory -> bf16 hi/lo -----------------------------
__global__ __launch_bounds__(256) void k_splitmem(const float* __restrict__ x,
        us* __restrict__ hi, us* __restrict__ lo, int n) {
    int i = blockIdx.x * 256 + threadIdx.x;
    const int stride = gridDim.x * 256;
    for (; i < n; i += stride) {
        us h, l;
        split2(x[i], &h, &l);
        hi[i] = h; lo[i] = l;
    }
}

// ---------------- K3: vh [B][H] -> vhT_hi [H][B] (hi only) -------------------
__global__ __launch_bounds__(256) void k_tx(const float* __restrict__ vh,
        us* __restrict__ vhT_hi) {
    const int d = blockIdx.x;
    const int b = blockIdx.y * 256 + threadIdx.x;
    vhT_hi[d * B + b] = f2bf(vh[b * H + d]);
}

// ---------------- K4: stats pass 1 (deferred-max sumexp over m) --------------
__global__ __launch_bounds__(256) void k_stats(const us* __restrict__ src_hi,
        const us* __restrict__ src_lo,
        const us* __restrict__ qt_hi, const us* __restrict__ qt_lo,
        int mchunk, float* __restrict__ pmax, float* __restrict__ psum) {
    __shared__ us lds[16384];
    const int tid = threadIdx.x;
    const int w = tid >> 6, l = tid & 63;
    const int lr = l & 15, g = l >> 4;
    const int brow = blockIdx.x * 128 + w * 32;
    const int m0b = blockIdx.y * mchunk;
    const int rq = l >> 4, cq = l & 15;
    bf8 qh[2][4], ql[2][4];
#pragma unroll
    for (int bt = 0; bt < 2; bt++)
#pragma unroll
        for (int kk = 0; kk < 4; kk++) {
            const int o = (brow + bt * 16 + lr) * H + kk * 32 + g * 8;
            qh[bt][kk] = ldb(qt_hi + o);
            ql[bt][kk] = ldb(qt_lo + o);
        }
    float mb[8], sm[8];
#pragma unroll
    for (int i = 0; i < 8; i++) { mb[i] = -INFINITY; sm[i] = 0.f; }
    auto STAGE = [&](int t, int bi) {
        const int m0 = m0b + t * 32;
        us* Q = lds + bi * 8192;
#pragma unroll
        for (int i = 0; i < 4; i++) {
            const int id = w * 4 + i;
            const int ii = id & 7;
            const int r = ii * 4 + rq;
            const int cc = cq ^ (r & 7);
            gload16((id < 8 ? src_hi : src_lo) + (size_t)(m0 + r) * H + cc * 8,
                    Q + (id < 8 ? 0 : 4096) + ii * 512);
        }
    };
    STAGE(0, 0);
    int cur = 0;
    const int NT = mchunk / 32;
    for (int t = 0; t < NT; t++) {
        if (t + 1 < NT) { STAGE(t + 1, cur ^ 1); VMWAIT(4); }
        else { VMWAIT(0); }
        SBAR();   // tile t fully landed (all waves)
        const us* Q = lds + cur * 8192;
        f32x4 c[2][2];
#pragma unroll
        for (int bt = 0; bt < 2; bt++)
#pragma unroll
            for (int mt = 0; mt < 2; mt++) c[bt][mt] = (f32x4){0.f, 0.f, 0.f, 0.f};
#pragma unroll
        for (int kk = 0; kk < 4; kk++) {
            const int co = ((kk * 4 + g) ^ (lr & 7)) * 8;
            bf8 b0h = *(const bf8*)(Q + lr * 128 + co);
            bf8 b0l = *(const bf8*)(Q + 4096 + lr * 128 + co);
            bf8 b1h = *(const bf8*)(Q + (16 + lr) * 128 + co);
            bf8 b1l = *(const bf8*)(Q + 4096 + (16 + lr) * 128 + co);
            c[0][0] = MFMA(qh[0][kk], b0h, c[0][0], 0, 0, 0);
            c[0][0] = MFMA(ql[0][kk], b0h, c[0][0], 0, 0, 0);
            c[0][0] = MFMA(qh[0][kk], b0l, c[0][0], 0, 0, 0);
            c[0][1] = MFMA(qh[0][kk], b1h, c[0][1], 0, 0, 0);
            c[0][1] = MFMA(ql[0][kk], b1h, c[0][1], 0, 0, 0);
            c[0][1] = MFMA(qh[0][kk], b1l, c[0][1], 0, 0, 0);
            c[1][0] = MFMA(qh[1][kk], b0h, c[1][0], 0, 0, 0);
            c[1][0] = MFMA(ql[1][kk], b0h, c[1][0], 0, 0, 0);
            c[1][0] = MFMA(qh[1][kk], b0l, c[1][0], 0, 0, 0);
            c[1][1] = MFMA(qh[1][kk], b1h, c[1][1], 0, 0, 0);
            c[1][1] = MFMA(ql[1][kk], b1h, c[1][1], 0, 0, 0);
            c[1][1] = MFMA(qh[1][kk], b1l, c[1][1], 0, 0, 0);
        }
        float dm = -INFINITY;
#pragma unroll
        for (int bt = 0; bt < 2; bt++)
#pragma unroll
            for (int mt = 0; mt < 2; mt++)
#pragma unroll
                for (int r = 0; r < 4; r++)
                    dm = fmaxf(dm, c[bt][mt][r] - mb[bt * 4 + r]);
        if (__any(dm > 8.f)) {
#pragma unroll
            for (int bt = 0; bt < 2; bt++)
#pragma unroll
                for (int r = 0; r < 4; r++) {
                    const int s = bt * 4 + r;
                    float mx = fmaxf(mb[s], fmaxf(c[bt][0][r], c[bt][1][r]));
                    sm[s] = sm[s] * __expf(mb[s] - mx)
                          + __expf(c[bt][0][r] - mx) + __expf(c[bt][1][r] - mx);
                    mb[s] = mx;
                }
        } else {
#pragma unroll
            for (int bt = 0; bt < 2; bt++)
#pragma unroll
                for (int r = 0; r < 4; r++) {
                    const int s = bt * 4 + r;
                    sm[s] += __expf(c[bt][0][r] - mb[s]) + __expf(c[bt][1][r] - mb[s]);
                }
        }
        if (t + 1 < NT) SBAR();   // all reads of buf[cur] done before next overwrite
        cur ^= 1;
    }
#pragma unroll
    for (int s = 0; s < 8; s++) {
#pragma unroll
        for (int x = 1; x < 16; x <<= 1) {
            float om = __shfl_xor(mb[s], x);
            float os = __shfl_xor(sm[s], x);
            float nm = fmaxf(mb[s], om);
            sm[s] = sm[s] * __expf(mb[s] - nm) + os * __expf(om - nm);
            mb[s] = nm;
        }
    }
    if (lr == 0) {
#pragma unroll
        for (int bt = 0; bt < 2; bt++)
#pragma unroll
            for (int r = 0; r < 4; r++) {
                const int row = brow + bt * 16 + g * 4 + r;
                pmax[row * SC + blockIdx.y] = mb[bt * 4 + r];
                psum[row * SC + blockIdx.y] = sm[bt * 4 + r];
            }
    }
}

// ---------------- K5: combine -> ffac[b] = exp(-gmax)/Z ----------------------
__global__ __launch_bounds__(256) void k_combine1(const float* __restrict__ pmax,
        const float* __restrict__ psum, float* __restrict__ ffac) {
    const int b = blockIdx.x * 256 + threadIdx.x;
    float mx = -INFINITY;
    for (int c = 0; c < SC; c++) mx = fmaxf(mx, pmax[b * SC + c]);
    float z = 0.f;
    for (int c = 0; c < SC; c++) z += psum[b * SC + c] * __expf(pmax[b * SC + c] - mx);
    ffac[b] = __expf(-mx) / z;
}

// ---------------- K6: update: memw = normalize(memory + P1^T @ vh) -----------
// Round-8 counted-vmcnt schedule + slot-swizzled P tile (bank fix).
// P tile row r, 8B-slot s stored at us r*PST + (s ^ (2*(r&3)))*4.
__global__ __launch_bounds__(256) void k_update(const float* __restrict__ memory,
        const us* __restrict__ mem_hi, const us* __restrict__ mem_lo,
        const us* __restrict__ qt_hi, const us* __restrict__ qt_lo,
        const us* __restrict__ vhT_hi, const float* __restrict__ ffac,
        us* __restrict__ memw_hi, us* __restrict__ memw_lo,
        us* __restrict__ memwT_hi) {
    __shared__ us lds[29696]; // qt dbuf 2x8192 | vhT 4096 | P 4x2304; epi reuses front
    const int tid = threadIdx.x;
    const int w = tid >> 6, l = tid & 63;
    const int lr = l & 15, g = l >> 4;
    const int mrow = blockIdx.x * 128 + w * 32;
    const int rq = l >> 4, cq = l & 15;
    const int rv = l >> 2, cv = l & 3;
    bf8 bh[2][4], bl[2][4];
#pragma unroll
    for (int t = 0; t < 2; t++)
#pragma unroll
        for (int kk = 0; kk < 4; kk++) {
            const int o = (mrow + t * 16 + lr) * H + kk * 32 + g * 8;
            bh[t][kk] = ldb(mem_hi + o);
            bl[t][kk] = ldb(mem_lo + o);
        }
    f32x4 acc[2][8];
#pragma unroll
    for (int t = 0; t < 2; t++)
#pragma unroll
        for (int dt = 0; dt < 8; dt++) acc[t][dt] = (f32x4){0.f, 0.f, 0.f, 0.f};
    us* Ph = lds + 20480 + w * 2304;
    us* Pl = Ph + 1152;
    auto STAGE_QT = [&](int t, int bi) {
        const int b0 = t * 32;
        us* Q = lds + bi * 8192;
#pragma unroll
        for (int i = 0; i < 4; i++) {
            const int id = w * 4 + i;
            const int ii = id & 7;
            const int r = ii * 4 + rq;
            const int cc = cq ^ (r & 7);
            gload16((id < 8 ? qt_hi : qt_lo) + (size_t)(b0 + r) * H + cc * 8,
                    Q + (id < 8 ? 0 : 4096) + ii * 512);
        }
    };
    auto STAGE_VH = [&](int t) {
        const int b0 = t * 32;
        us* V = lds + 16384;
#pragma unroll
        for (int i = 0; i < 2; i++) {
            const int j = w * 2 + i;
            const int r = j * 16 + rv;
            const int cc = cv ^ ((rv >> 1) & 3);
            gload16(vhT_hi + (size_t)r * B + b0 + cc * 8, V + j * 512);
        }
    };
    STAGE_QT(0, 0);
    STAGE_VH(0);
    int cur = 0;
    const int NT = B / 32;
    const us* V = lds + 16384;
    for (int t = 0; t < NT; t++) {
        if (t + 1 < NT) { STAGE_QT(t + 1, cur ^ 1); VMWAIT(6); }
        else { VMWAIT(2); }
        SBAR();   // Q(t) landed for all waves
        const us* Q = lds + cur * 8192;
        f32x4 c[2][2];
#pragma unroll
        for (int bt = 0; bt < 2; bt++)
#pragma unroll
            for (int mt = 0; mt < 2; mt++) c[bt][mt] = (f32x4){0.f, 0.f, 0.f, 0.f};
#pragma unroll
        for (int kk = 0; kk < 4; kk++) {
            const int co = ((kk * 4 + g) ^ (lr & 7)) * 8;
            bf8 a0h = *(const bf8*)(Q + lr * 128 + co);
            bf8 a0l = *(const bf8*)(Q + 4096 + lr * 128 + co);
            bf8 a1h = *(const bf8*)(Q + (16 + lr) * 128 + co);
            bf8 a1l = *(const bf8*)(Q + 4096 + (16 + lr) * 128 + co);
            c[0][0] = MFMA(a0h, bh[0][kk], c[0][0], 0, 0, 0);
            c[0][0] = MFMA(a0l, bh[0][kk], c[0][0], 0, 0, 0);
            c[0][0] = MFMA(a0h, bl[0][kk], c[0][0], 0, 0, 0);
            c[0][1] = MFMA(a0h, bh[1][kk], c[0][1], 0, 0, 0);
            c[0][1] = MFMA(a0l, bh[1][kk], c[0][1], 0, 0, 0);
            c[0][1] = MFMA(a0h, bl[1][kk], c[0][1], 0, 0, 0);
            c[1][0] = MFMA(a1h, bh[0][kk], c[1][0], 0, 0, 0);
            c[1][0] = MFMA(a1l, bh[0][kk], c[1][0], 0, 0, 0);
            c[1][0] = MFMA(a1h, bl[0][kk], c[1][0], 0, 0, 0);
            c[1][1] = MFMA(a1h, bh[1][kk], c[1][1], 0, 0, 0);
            c[1][1] = MFMA(a1l, bh[1][kk], c[1][1], 0, 0, 0);
            c[1][1] = MFMA(a1h, bl[1][kk], c[1][1], 0, 0, 0);
        }
        const int b0 = t * 32;
        const float4 f4a = *(const float4*)(ffac + b0 + g * 4);
        const float4 f4b = *(const float4*)(ffac + b0 + 16 + g * 4);
        float fa[4] = {f4a.x, f4a.y, f4a.z, f4a.w};
        float fb[4] = {f4b.x, f4b.y, f4b.z, f4b.w};
        const int ksw = 2 * (lr & 3);   // even XOR keeps 8B slots / 16B pairs intact
#pragma unroll
        for (int bt = 0; bt < 2; bt++) {
#pragma unroll
            for (int mt = 0; mt < 2; mt++) {
                us hh[4], ll[4];
#pragma unroll
                for (int r = 0; r < 4; r++) {
                    float p = __expf(c[bt][mt][r]) * (bt ? fb[r] : fa[r]);
                    split2t(p, &hh[r], &ll[r]);
                }
                uint2 v;
                v.x = (unsigned)hh[0] | ((unsigned)hh[1] << 16);
                v.y = (unsigned)hh[2] | ((unsigned)hh[3] << 16);
                const int so = (mt * 16 + lr) * PST + ((bt * 4 + g) ^ ksw) * 4;
                *(uint2*)(Ph + so) = v;
                v.x = (unsigned)ll[0] | ((unsigned)ll[1] << 16);
                v.y = (unsigned)ll[2] | ((unsigned)ll[3] << 16);
                *(uint2*)(Pl + so) = v;
            }
        }
        bf8 pah[2], pal[2];
#pragma unroll
        for (int mt = 0; mt < 2; mt++) {
            const int ro = (mt * 16 + lr) * PST + (g ^ (lr & 3)) * 8;
            pah[mt] = *(const bf8*)(Ph + ro);
            pal[mt] = *(const bf8*)(Pl + ro);
        }
        if (t + 1 < NT) { VMWAIT(4); } else { VMWAIT(0); }
        SBAR();   // V(t) landed
#pragma unroll
        for (int dt = 0; dt < 8; dt++) {
            bf8 vhh = *(const bf8*)(V + (dt * 16 + lr) * 32
                                      + ((g ^ ((lr >> 1) & 3)) * 8));
            acc[0][dt] = MFMA(pah[0], vhh, acc[0][dt], 0, 0, 0);
            acc[0][dt] = MFMA(pal[0], vhh, acc[0][dt], 0, 0, 0);
            acc[1][dt] = MFMA(pah[1], vhh, acc[1][dt], 0, 0, 0);
            acc[1][dt] = MFMA(pal[1], vhh, acc[1][dt], 0, 0, 0);
        }
        if (t + 1 < NT) {
            SBAR();   // PV reads of V done; Q[cur] reads done
            STAGE_VH(t + 1);
        }
        cur ^= 1;
    }
    // epilogue: new = memory + acc; L2-normalize; write memw_hi/lo + memwT_hi
    float n2[2][4];
#pragma unroll
    for (int t = 0; t < 2; t++)
#pragma unroll
        for (int r = 0; r < 4; r++) n2[t][r] = 0.f;
#pragma unroll
    for (int t = 0; t < 2; t++)
#pragma unroll
        for (int dt = 0; dt < 8; dt++)
#pragma unroll
            for (int r = 0; r < 4; r++) {
                float v = acc[t][dt][r]
                        + memory[(mrow + t * 16 + g * 4 + r) * H + dt * 16 + lr];
                acc[t][dt][r] = v;
                n2[t][r] += v * v;
            }
#pragma unroll
    for (int t = 0; t < 2; t++)
#pragma unroll
        for (int r = 0; r < 4; r++) {
#pragma unroll
            for (int x = 1; x < 16; x <<= 1) n2[t][r] += __shfl_xor(n2[t][r], x);
            n2[t][r] = 1.f / fmaxf(sqrtf(n2[t][r]), 1e-12f);
        }
#pragma unroll
    for (int t = 0; t < 2; t++)
#pragma unroll
        for (int dt = 0; dt < 8; dt++)
#pragma unroll
            for (int r = 0; r < 4; r++) {
                float vv = acc[t][dt][r] * n2[t][r];
                us h, lo2;
                split2t(vv, &h, &lo2);
                memw_hi[(mrow + t * 16 + g * 4 + r) * H + dt * 16 + lr] = h;
                memw_lo[(mrow + t * 16 + g * 4 + r) * H + dt * 16 + lr] = lo2;
            }
    __syncthreads();
#pragma unroll
    for (int t = 0; t < 2; t++)
#pragma unroll
        for (int dt = 0; dt < 8; dt++)
#pragma unroll
            for (int r = 0; r < 4; r++) {
                float vv = acc[t][dt][r] * n2[t][r];
                lds[(dt * 16 + lr) * 136 + w * 32 + t * 16 + g * 4 + r]
                    = (us)(__float_as_uint(vv) >> 16);
            }
    __syncthreads();
    {
        const int d = tid >> 1, seg = tid & 1;
        uint4* dq = (uint4*)(memwT_hi + (size_t)d * M + blockIdx.x * 128 + seg * 64);
        const uint4* sp = (const uint4*)(lds + d * 136 + seg * 64);
#pragma unroll
        for (int j = 0; j < 8; j++) dq[j] = sp[j];
    }
}

// ---------------- K7: flash read: fused stats2 + PV over m-chunks ------------
__global__ __launch_bounds__(256) void k_fread(const us* __restrict__ memw_hi,
        const us* __restrict__ memw_lo, const us* __restrict__ memwT_hi,
        const us* __restrict__ qt_hi, const us* __restrict__ qt_lo,
        float* __restrict__ part, float* __restrict__ pmax2,
        float* __restrict__ psum2, int mchunk) {
    __shared__ us lds[29696];
    const int tid = threadIdx.x;
    const int w = tid >> 6, l = tid & 63;
    const int lr = l & 15, g = l >> 4;
    const int brow = blockIdx.x * 128 + w * 32;
    const int m0b = blockIdx.y * mchunk;
    const int rq = l >> 4, cq = l & 15;
    const int rv = l >> 2, cv = l & 3;
    bf8 qh[2][4], ql[2][4];
#pragma unroll
    for (int bt = 0; bt < 2; bt++)
#pragma unroll
        for (int kk = 0; kk < 4; kk++) {
            const int o = (brow + bt * 16 + lr) * H + kk * 32 + g * 8;
            qh[bt][kk] = ldb(qt_hi + o);
            ql[bt][kk] = ldb(qt_lo + o);
        }
    f32x4 acc[2][8];
#pragma unroll
    for (int bt = 0; bt < 2; bt++)
#pragma unroll
        for (int dt = 0; dt < 8; dt++) acc[bt][dt] = (f32x4){0.f, 0.f, 0.f, 0.f};
    float mb0 = 0.f, sm0 = 0.f, mb1 = 0.f, sm1 = 0.f;
    us* Ph = lds + 20480 + w * 2304;
    us* Pl = Ph + 1152;
    auto STAGE_MW = [&](int t, int bi) {
        const int m0 = m0b + t * 32;
        us* Q = lds + bi * 8192;
#pragma unroll
        for (int i = 0; i < 4; i++) {
            const int id = w * 4 + i;
            const int ii = id & 7;
            const int r = ii * 4 + rq;
            const int cc = cq ^ (r & 7);
            gload16((id < 8 ? memw_hi : memw_lo) + (size_t)(m0 + r) * H + cc * 8,
                    Q + (id < 8 ? 0 : 4096) + ii * 512);
        }
    };
    auto STAGE_WT = [&](int t) {
        const int m0 = m0b + t * 32;
        us* V = lds + 16384;
#pragma unroll
        for (int i = 0; i < 2; i++) {
            const int j = w * 2 + i;
            const int r = j * 16 + rv;
            const int cc = cv ^ ((rv >> 1) & 3);
            gload16(memwT_hi + (size_t)r * M + m0 + cc * 8, V + j * 512);
        }
    };
    STAGE_MW(0, 0);
    STAGE_WT(0);
    int cur = 0;
    const int NT = mchunk / 32;
    const us* V = lds + 16384;
    for (int t = 0; t < NT; t++) {
        if (t + 1 < NT) { STAGE_MW(t + 1, cur ^ 1); VMWAIT(6); }
        else { VMWAIT(2); }
        SBAR();   // memw tile t landed
        const us* Q = lds + cur * 8192;
        f32x4 c[2][2];
#pragma unroll
        for (int mt = 0; mt < 2; mt++)
#pragma unroll
            for (int bt = 0; bt < 2; bt++) c[mt][bt] = (f32x4){0.f, 0.f, 0.f, 0.f};
#pragma unroll
        for (int kk = 0; kk < 4; kk++) {
            const int co = ((kk * 4 + g) ^ (lr & 7)) * 8;
            bf8 a0h = *(const bf8*)(Q + lr * 128 + co);
            bf8 a0l = *(const bf8*)(Q + 4096 + lr * 128 + co);
            bf8 a1h = *(const bf8*)(Q + (16 + lr) * 128 + co);
            bf8 a1l = *(const bf8*)(Q + 4096 + (16 + lr) * 128 + co);
            c[0][0] = MFMA(a0h, qh[0][kk], c[0][0], 0, 0, 0);
            c[0][0] = MFMA(a0l, qh[0][kk], c[0][0], 0, 0, 0);
            c[0][0] = MFMA(a0h, ql[0][kk], c[0][0], 0, 0, 0);
            c[0][1] = MFMA(a0h, qh[1][kk], c[0][1], 0, 0, 0);
            c[0][1] = MFMA(a0l, qh[1][kk], c[0][1], 0, 0, 0);
            c[0][1] = MFMA(a0h, ql[1][kk], c[0][1], 0, 0, 0);
            c[1][0] = MFMA(a1h, qh[0][kk], c[1][0], 0, 0, 0);
            c[1][0] = MFMA(a1l, qh[0][kk], c[1][0], 0, 0, 0);
            c[1][0] = MFMA(a1h, ql[0][kk], c[1][0], 0, 0, 0);
            c[1][1] = MFMA(a1h, qh[1][kk], c[1][1], 0, 0, 0);
            c[1][1] = MFMA(a1l, qh[1][kk], c[1][1], 0, 0, 0);
            c[1][1] = MFMA(a1h, ql[1][kk], c[1][1], 0, 0, 0);
        }
        float s[2][2][4];
        float lmax0 = -INFINITY, lmax1 = -INFINITY;
#pragma unroll
        for (int mt = 0; mt < 2; mt++)
#pragma unroll
            for (int r = 0; r < 4; r++) {
                s[mt][0][r] = c[mt][0][r] * SCALE2;
                s[mt][1][r] = c[mt][1][r] * SCALE2;
                lmax0 = fmaxf(lmax0, s[mt][0][r]);
                lmax1 = fmaxf(lmax1, s[mt][1][r]);
            }
        lmax0 = fmaxf(lmax0, __shfl_xor(lmax0, 16));
        lmax0 = fmaxf(lmax0, __shfl_xor(lmax0, 32));
        lmax1 = fmaxf(lmax1, __shfl_xor(lmax1, 16));
        lmax1 = fmaxf(lmax1, __shfl_xor(lmax1, 32));
        if (__any((lmax0 > mb0 + 8.f) || (lmax1 > mb1 + 8.f))) {
            float nm0 = fmaxf(mb0, lmax0), f0 = __expf(mb0 - nm0);
            float nm1 = fmaxf(mb1, lmax1), f1 = __expf(mb1 - nm1);
            sm0 *= f0; sm1 *= f1;
            float fr0[4], fr1[4];
#pragma unroll
            for (int r = 0; r < 4; r++) {
                fr0[r] = __shfl(f0, g * 4 + r);
                fr1[r] = __shfl(f1, g * 4 + r);
            }
#pragma unroll
            for (int dt = 0; dt < 8; dt++)
#pragma unroll
                for (int r = 0; r < 4; r++) {
                    acc[0][dt][r] *= fr0[r];
                    acc[1][dt][r] *= fr1[r];
                }
            mb0 = nm0; mb1 = nm1;
        }
        const int ksw = 2 * (lr & 3);
#pragma unroll
        for (int bt = 0; bt < 2; bt++) {
            const float mbx = bt ? mb1 : mb0;
#pragma unroll
            for (int mt = 0; mt < 2; mt++) {
                us hh[4], ll[4];
#pragma unroll
                for (int r = 0; r < 4; r++) {
                    float p = __expf(s[mt][bt][r] - mbx);
                    if (bt) sm1 += p; else sm0 += p;
                    split2t(p, &hh[r], &ll[r]);
                }
                uint2 v;
                v.x = (unsigned)hh[0] | ((unsigned)hh[1] << 16);
                v.y = (unsigned)hh[2] | ((unsigned)hh[3] << 16);
                const int so = (bt * 16 + lr) * PST + ((mt * 4 + g) ^ ksw) * 4;
                *(uint2*)(Ph + so) = v;
                v.x = (unsigned)ll[0] | ((unsigned)ll[1] << 16);
                v.y = (unsigned)ll[2] | ((unsigned)ll[3] << 16);
                *(uint2*)(Pl + so) = v;
            }
        }
        bf8 pah[2], pal[2];
#pragma unroll
        for (int bt = 0; bt < 2; bt++) {
            const int ro = (bt * 16 + lr) * PST + (g ^ (lr & 3)) * 8;
            pah[bt] = *(const bf8*)(Ph + ro);
            pal[bt] = *(const bf8*)(Pl + ro);
        }
        if (t + 1 < NT) { VMWAIT(4); } else { VMWAIT(0); }
        SBAR();   // memwT tile t landed
#pragma unroll
        for (int dt = 0; dt < 8; dt++) {
            bf8 th = *(const bf8*)(V + (dt * 16 + lr) * 32
                                     + ((g ^ ((lr >> 1) & 3)) * 8));
            acc[0][dt] = MFMA(pah[0], th, acc[0][dt], 0, 0, 0);
            acc[0][dt] = MFMA(pal[0], th, acc[0][dt], 0, 0, 0);
            acc[1][dt] = MFMA(pah[1], th, acc[1][dt], 0, 0, 0);
            acc[1][dt] = MFMA(pal[1], th, acc[1][dt], 0, 0, 0);
        }
        if (t + 1 < NT) {
            SBAR();   // PV reads done
            STAGE_WT(t + 1);
        }
        cur ^= 1;
    }
    sm0 += __shfl_xor(sm0, 16); sm0 += __shfl_xor(sm0, 32);
    sm1 += __shfl_xor(sm1, 16); sm1 += __shfl_xor(sm1, 32);
    if (g == 0) {
        pmax2[(size_t)blockIdx.y * B + brow + lr] = mb0;
        psum2[(size_t)blockIdx.y * B + brow + lr] = sm0;
        pmax2[(size_t)blockIdx.y * B + brow + 16 + lr] = mb1;
        psum2[(size_t)blockIdx.y * B + brow + 16 + lr] = sm1;
    }
    float* rp = part + (size_t)blockIdx.y * B * H;
#pragma unroll
    for (int bt = 0; bt < 2; bt++)
#pragma unroll
        for (int dt = 0; dt < 8; dt++)
#pragma unroll
            for (int r = 0; r < 4; r++)
                rp[(size_t)(brow + bt * 16 + g * 4 + r) * H + dt * 16 + lr] =
                    acc[bt][dt][r];
}

// ---------------- K8: per-b chunk weights ------------------------------------
__global__ __launch_bounds__(256) void k_fstats(const float* __restrict__ pmax2,
        const float* __restrict__ psum2, float* __restrict__ wc, int nc) {
    const int b = blockIdx.x * 256 + threadIdx.x;
    float gm = -INFINITY;
    for (int c = 0; c < nc; c++) gm = fmaxf(gm, pmax2[(size_t)c * B + b]);
    float z = 0.f;
    for (int c = 0; c < nc; c++)
        z += psum2[(size_t)c * B + b] * __expf(pmax2[(size_t)c * B + b] - gm);
    const float zi = 1.f / z;
    for (int c = 0; c < nc; c++)
        wc[(size_t)c * B + b] = __expf(pmax2[(size_t)c * B + b] - gm) * zi;
}

// ---------------- K9: weighted combine -> out --------------------------------
__global__ __launch_bounds__(256) void k_fcombine(const float* __restrict__ part,
        const float* __restrict__ wc, float* __restrict__ out, int nc) {
    const int i = blockIdx.x * 256 + threadIdx.x;
    const int b = i >> 7;
    float s = 0.f;
    for (int c = 0; c < nc; c++) s += part[(size_t)c * B * H + i] * wc[(size_t)c * B + b];
    out[i] = s;
}

extern "C" void kernel_launch(void* const* d_in, const int* in_sizes, int n_in,
                              void* d_out, int out_size, void* d_ws, size_t ws_size,
                              hipStream_t stream) {
    const float* ts     = (const float*)d_in[0];
    const float* inp    = (const float*)d_in[1];
    const float* memory = (const float*)d_in[2];
    const float* w_t    = (const float*)d_in[3];
    const float* b_t    = (const float*)d_in[4];
    const float* Wq     = (const float*)d_in[5];
    const float* Wk     = (const float*)d_in[6];
    const float* Wv     = (const float*)d_in[7];
    float* out = (float*)d_out;

    char* p = (char*)d_ws;
    auto alloc = [&](size_t bytes) { char* r = p; p += (bytes + 255) & ~(size_t)255; return r; };
    us* mem_hi   = (us*)alloc((size_t)M * H * 2);
    us* mem_lo   = (us*)alloc((size_t)M * H * 2);
    us* memw_hi  = (us*)alloc((size_t)M * H * 2);
    us* memw_lo  = (us*)alloc((size_t)M * H * 2);
    us* memwT_hi = (us*)alloc((size_t)M * H * 2);
    us* qt_hi    = (us*)alloc((size_t)B * H * 2);
    us* qt_lo    = (us*)alloc((size_t)B * H * 2);
    us* vhT_hi   = (us*)alloc((size_t)B * H * 2);
    float* vh    = (float*)alloc((size_t)B * H * 4);
    float* pmax  = (float*)alloc((size_t)B * SC * 4);
    float* psum  = (float*)alloc((size_t)B * SC * 4);
    float* ffac  = (float*)alloc((size_t)B * 4);
    size_t remain = ws_size - (size_t)(p - (char*)d_ws);
    int NC = 1;
    for (int c = 32; c >= 1; c >>= 1) {
        size_t need = (size_t)c * B * H * 4 + 3 * (size_t)c * B * 4 + 4096;
        if (need <= remain) { NC = c; break; }
    }
    float* pmax2 = (float*)alloc((size_t)NC * B * 4);
    float* psum2 = (float*)alloc((size_t)NC * B * 4);
    float* wcb   = (float*)alloc((size_t)NC * B * 4);
    float* part  = (float*)alloc((size_t)NC * B * H * 4);
    const int mchunk = M / NC;

    hipLaunchKernelGGL(k_prep, dim3(B), dim3(128), 0, stream,
                       ts, inp, w_t, b_t, Wq, Wk, Wv, qt_hi, qt_lo, vh);
    hipLaunchKernelGGL(k_splitmem, dim3(2048), dim3(256), 0, stream,
                       memory, mem_hi, mem_lo, M * H);
    hipLaunchKernelGGL(k_tx, dim3(H, B / 256), dim3(256), 0, stream, vh, vhT_hi);
    hipLaunchKernelGGL(k_stats, dim3(B / 128, SC), dim3(256), 0, stream,
                       mem_hi, mem_lo, qt_hi, qt_lo, M / SC, pmax, psum);
    hipLaunchKernelGGL(k_combine1, dim3(B / 256), dim3(256), 0, stream, pmax, psum, ffac);
    hipLaunchKernelGGL(k_update, dim3(M / 128), dim3(256), 0, stream,
                       memory, mem_hi, mem_lo, qt_hi, qt_lo, vhT_hi,
                       ffac, memw_hi, memw_lo, memwT_hi);
    hipLaunchKernelGGL(k_fread, dim3(B / 128, NC), dim3(256), 0, stream,
                       memw_hi, memw_lo, memwT_hi, qt_hi, qt_lo,
                       part, pmax2, psum2, mchunk);
    hipLaunchKernelGGL(k_fstats, dim3(B / 256), dim3(256), 0, stream, pmax2, psum2, wcb, NC);
    hipLaunchKernelGGL(k_fcombine, dim3(B * H / 256), dim3(256), 0, stream, part, wcb, out, NC);
}

// Round 11
// 573.972 us; speedup vs baseline: 1.6296x; 1.3465x over previous
//
#include <hip/hip_runtime.h>
#include <math.h>

#define B 2048
#define M 65536
#define H 128
#define TDIM 128
#define IDIM 256
#define SC 32            // stats-1 chunks over M
#define SCALE2 0.08838834764831845f
#define PST 36           // P-tile row stride (us units); slots XOR-swizzled within row

typedef short bf8 __attribute__((ext_vector_type(8)));
typedef float f32x4 __attribute__((ext_vector_type(4)));
#define MFMA __builtin_amdgcn_mfma_f32_16x16x32_bf16
typedef unsigned short us;

#define SBAR() do { __builtin_amdgcn_sched_barrier(0); \
                    __builtin_amdgcn_s_barrier(); \
                    __builtin_amdgcn_sched_barrier(0); } while (0)
#define VMWAIT(N) do { asm volatile("s_waitcnt vmcnt(" #N ")" ::: "memory"); \
                       __builtin_amdgcn_sched_barrier(0); } while (0)
#define SCHED_FENCE() __builtin_amdgcn_sched_barrier(0)

__device__ inline us f2bf(float x) {
    unsigned u = __float_as_uint(x);
    u += 0x7FFF + ((u >> 16) & 1);
    return (us)(u >> 16);
}
__device__ inline float bf2f(us h) { return __uint_as_float(((unsigned)h) << 16); }
__device__ inline void split2(float x, us* hi, us* lo) {
    us h = f2bf(x); *hi = h; *lo = f2bf(x - bf2f(h));
}
__device__ inline void split2t(float x, us* hi, us* lo) {
    us h = (us)(__float_as_uint(x) >> 16);
    *hi = h; *lo = f2bf(x - bf2f(h));
}
__device__ inline bf8 ldb(const us* p) { return *(const bf8*)p; }
__device__ inline void gload16(const void* g, void* l) {
    __builtin_amdgcn_global_load_lds(
        (const __attribute__((address_space(1))) unsigned int*)g,
        (__attribute__((address_space(3))) unsigned int*)l, 16, 0, 0);
}

// ---------------- K1: prep: qt = ((cos-enc)@Wq^T)@Wk -> bf16 hi/lo; vh fp32 --
__global__ __launch_bounds__(128) void k_prep(const float* __restrict__ ts,
        const float* __restrict__ inp, const float* __restrict__ w_t,
        const float* __restrict__ b_t, const float* __restrict__ Wq,
        const float* __restrict__ Wk, const float* __restrict__ Wv,
        us* __restrict__ qt_hi, us* __restrict__ qt_lo, float* __restrict__ vh) {
    __shared__ float temb[TDIM];
    __shared__ float qh[H];
    const int b = blockIdx.x, t = threadIdx.x;
    temb[t] = cosf(ts[b] * w_t[t] + b_t[t]);
    __syncthreads();
    float s = 0.f;
    for (int k = 0; k < TDIM; k++) s += temb[k] * Wq[t * TDIM + k];
    qh[t] = s;
    __syncthreads();
    float s2 = 0.f;
    for (int j = 0; j < H; j++) s2 += qh[j] * Wk[j * H + t];
    us h, l;
    split2(s2, &h, &l);
    qt_hi[b * H + t] = h; qt_lo[b * H + t] = l;
    float s3 = 0.f;
    for (int i = 0; i < IDIM; i++) s3 += inp[b * IDIM + i] * Wv[t * IDIM + i];
    vh[b * H + t] = s3;
}

// ---------------- K2: split memory -> bf16 hi/lo -----------------------------
__global__ __launch_bounds__(256) void k_splitmem(const float* __restrict__ x,
        us* __restrict__ hi, us* __restrict__ lo, int n) {
    int i = blockIdx.x * 256 + threadIdx.x;
    const int stride = gridDim.x * 256;
    for (; i < n; i += stride) {
        us h, l;
        split2(x[i], &h, &l);
        hi[i] = h; lo[i] = l;
    }
}

// ---------------- K3: vh [B][H] -> vhT_hi [H][B] (hi only) -------------------
__global__ __launch_bounds__(256) void k_tx(const float* __restrict__ vh,
        us* __restrict__ vhT_hi) {
    const int d = blockIdx.x;
    const int b = blockIdx.y * 256 + threadIdx.x;
    vhT_hi[d * B + b] = f2bf(vh[b * H + d]);
}

// ---------------- K4: stats pass 1 (deferred-max sumexp over m) --------------
__global__ __launch_bounds__(256) void k_stats(const us* __restrict__ src_hi,
        const us* __restrict__ src_lo,
        const us* __restrict__ qt_hi, const us* __restrict__ qt_lo,
        int mchunk, float* __restrict__ pmax, float* __restrict__ psum) {
    __shared__ us lds[16384];
    const int tid = threadIdx.x;
    const int w = tid >> 6, l = tid & 63;
    const int lr = l & 15, g = l >> 4;
    const int brow = blockIdx.x * 128 + w * 32;
    const int m0b = blockIdx.y * mchunk;
    const int rq = l >> 4, cq = l & 15;
    bf8 qh[2][4], ql[2][4];
#pragma unroll
    for (int bt = 0; bt < 2; bt++)
#pragma unroll
        for (int kk = 0; kk < 4; kk++) {
            const int o = (brow + bt * 16 + lr) * H + kk * 32 + g * 8;
            qh[bt][kk] = ldb(qt_hi + o);
            ql[bt][kk] = ldb(qt_lo + o);
        }
    float mb[8], sm[8];
#pragma unroll
    for (int i = 0; i < 8; i++) { mb[i] = -INFINITY; sm[i] = 0.f; }
    auto STAGE = [&](int t, int bi) {
        const int m0 = m0b + t * 32;
        us* Q = lds + bi * 8192;
#pragma unroll
        for (int i = 0; i < 4; i++) {
            const int id = w * 4 + i;
            const int ii = id & 7;
            const int r = ii * 4 + rq;
            const int cc = cq ^ (r & 7);
            gload16((id < 8 ? src_hi : src_lo) + (size_t)(m0 + r) * H + cc * 8,
                    Q + (id < 8 ? 0 : 4096) + ii * 512);
        }
    };
    STAGE(0, 0);
    int cur = 0;
    const int NT = mchunk / 32;
    for (int t = 0; t < NT; t++) {
        if (t + 1 < NT) { STAGE(t + 1, cur ^ 1); VMWAIT(4); }
        else { VMWAIT(0); }
        SBAR();
        const us* Q = lds + cur * 8192;
        f32x4 c[2][2];
#pragma unroll
        for (int bt = 0; bt < 2; bt++)
#pragma unroll
            for (int mt = 0; mt < 2; mt++) c[bt][mt] = (f32x4){0.f, 0.f, 0.f, 0.f};
#pragma unroll
        for (int kk = 0; kk < 4; kk++) {
            const int co = ((kk * 4 + g) ^ (lr & 7)) * 8;
            bf8 b0h = *(const bf8*)(Q + lr * 128 + co);
            bf8 b0l = *(const bf8*)(Q + 4096 + lr * 128 + co);
            bf8 b1h = *(const bf8*)(Q + (16 + lr) * 128 + co);
            bf8 b1l = *(const bf8*)(Q + 4096 + (16 + lr) * 128 + co);
            c[0][0] = MFMA(qh[0][kk], b0h, c[0][0], 0, 0, 0);
            c[0][0] = MFMA(ql[0][kk], b0h, c[0][0], 0, 0, 0);
            c[0][0] = MFMA(qh[0][kk], b0l, c[0][0], 0, 0, 0);
            c[0][1] = MFMA(qh[0][kk], b1h, c[0][1], 0, 0, 0);
            c[0][1] = MFMA(ql[0][kk], b1h, c[0][1], 0, 0, 0);
            c[0][1] = MFMA(qh[0][kk], b1l, c[0][1], 0, 0, 0);
            c[1][0] = MFMA(qh[1][kk], b0h, c[1][0], 0, 0, 0);
            c[1][0] = MFMA(ql[1][kk], b0h, c[1][0], 0, 0, 0);
            c[1][0] = MFMA(qh[1][kk], b0l, c[1][0], 0, 0, 0);
            c[1][1] = MFMA(qh[1][kk], b1h, c[1][1], 0, 0, 0);
            c[1][1] = MFMA(ql[1][kk], b1h, c[1][1], 0, 0, 0);
            c[1][1] = MFMA(qh[1][kk], b1l, c[1][1], 0, 0, 0);
        }
        float dm = -INFINITY;
#pragma unroll
        for (int bt = 0; bt < 2; bt++)
#pragma unroll
            for (int mt = 0; mt < 2; mt++)
#pragma unroll
                for (int r = 0; r < 4; r++)
                    dm = fmaxf(dm, c[bt][mt][r] - mb[bt * 4 + r]);
        if (__any(dm > 8.f)) {
#pragma unroll
            for (int bt = 0; bt < 2; bt++)
#pragma unroll
                for (int r = 0; r < 4; r++) {
                    const int s = bt * 4 + r;
                    float mx = fmaxf(mb[s], fmaxf(c[bt][0][r], c[bt][1][r]));
                    sm[s] = sm[s] * __expf(mb[s] - mx)
                          + __expf(c[bt][0][r] - mx) + __expf(c[bt][1][r] - mx);
                    mb[s] = mx;
                }
        } else {
#pragma unroll
            for (int bt = 0; bt < 2; bt++)
#pragma unroll
                for (int r = 0; r < 4; r++) {
                    const int s = bt * 4 + r;
                    sm[s] += __expf(c[bt][0][r] - mb[s]) + __expf(c[bt][1][r] - mb[s]);
                }
        }
        if (t + 1 < NT) SBAR();
        cur ^= 1;
    }
#pragma unroll
    for (int s = 0; s < 8; s++) {
#pragma unroll
        for (int x = 1; x < 16; x <<= 1) {
            float om = __shfl_xor(mb[s], x);
            float os = __shfl_xor(sm[s], x);
            float nm = fmaxf(mb[s], om);
            sm[s] = sm[s] * __expf(mb[s] - nm) + os * __expf(om - nm);
            mb[s] = nm;
        }
    }
    if (lr == 0) {
#pragma unroll
        for (int bt = 0; bt < 2; bt++)
#pragma unroll
            for (int r = 0; r < 4; r++) {
                const int row = brow + bt * 16 + g * 4 + r;
                pmax[row * SC + blockIdx.y] = mb[bt * 4 + r];
                psum[row * SC + blockIdx.y] = sm[bt * 4 + r];
            }
    }
}

// ---------------- K5: combine -> ffac[b] = exp(-gmax)/Z ----------------------
__global__ __launch_bounds__(256) void k_combine1(const float* __restrict__ pmax,
        const float* __restrict__ psum, float* __restrict__ ffac) {
    const int b = blockIdx.x * 256 + threadIdx.x;
    float mx = -INFINITY;
    for (int c = 0; c < SC; c++) mx = fmaxf(mx, pmax[b * SC + c]);
    float z = 0.f;
    for (int c = 0; c < SC; c++) z += psum[b * SC + c] * __expf(pmax[b * SC + c] - mx);
    ffac[b] = __expf(-mx) / z;
}

// ---------------- K6: update (8 waves x 16 m-rows) ---------------------------
// LDS: Q dbuf [0,16384) | V [16384,20480) | P [20480,29696); epi reuses front.
// ffac loads hoisted BEFORE STAGE so their implicit vmcnt doesn't drain prefetch.
__global__ __launch_bounds__(512, 4) void k_update(const float* __restrict__ memory,
        const us* __restrict__ mem_hi, const us* __restrict__ mem_lo,
        const us* __restrict__ qt_hi, const us* __restrict__ qt_lo,
        const us* __restrict__ vhT_hi, const float* __restrict__ ffac,
        us* __restrict__ memw_hi, us* __restrict__ memw_lo,
        us* __restrict__ memwT_hi) {
    __shared__ us lds[29696];
    const int tid = threadIdx.x;
    const int w = tid >> 6, l = tid & 63;
    const int lr = l & 15, g = l >> 4;
    const int mrow = blockIdx.x * 128 + w * 16;
    const int rq = l >> 4, cq = l & 15;
    const int rv = l >> 2, cv = l & 3;
    bf8 bh[4], bl[4];
#pragma unroll
    for (int kk = 0; kk < 4; kk++) {
        const int o = (mrow + lr) * H + kk * 32 + g * 8;
        bh[kk] = ldb(mem_hi + o);
        bl[kk] = ldb(mem_lo + o);
    }
    f32x4 acc[8];
#pragma unroll
    for (int dt = 0; dt < 8; dt++) acc[dt] = (f32x4){0.f, 0.f, 0.f, 0.f};
    us* Ph = lds + 20480 + w * 1152;
    us* Pl = Ph + 576;
    auto STAGE_QT = [&](int t, int bi) {
        const int b0 = t * 32;
        us* Q = lds + bi * 8192;
#pragma unroll
        for (int i = 0; i < 2; i++) {
            const int id = w * 2 + i;
            const int ii = id & 7;
            const int r = ii * 4 + rq;
            const int cc = cq ^ (r & 7);
            gload16((id < 8 ? qt_hi : qt_lo) + (size_t)(b0 + r) * H + cc * 8,
                    Q + (id < 8 ? 0 : 4096) + ii * 512);
        }
    };
    auto STAGE_VH = [&](int t) {
        const int b0 = t * 32;
        us* V = lds + 16384;
        const int r = w * 16 + rv;
        const int cc = cv ^ ((rv >> 1) & 3);
        gload16(vhT_hi + (size_t)r * B + b0 + cc * 8, V + w * 512);
    };
    STAGE_QT(0, 0);
    STAGE_VH(0);
    int cur = 0;
    const int NT = B / 32;
    const us* V = lds + 16384;
    for (int t = 0; t < NT; t++) {
        const int b0 = t * 32;
        const float4 f4a = *(const float4*)(ffac + b0 + g * 4);
        const float4 f4b = *(const float4*)(ffac + b0 + 16 + g * 4);
        SCHED_FENCE();
        if (t + 1 < NT) { STAGE_QT(t + 1, cur ^ 1); SCHED_FENCE(); VMWAIT(5); }
        else { VMWAIT(3); }
        SBAR();   // Q(t) landed for all waves
        const us* Q = lds + cur * 8192;
        f32x4 c[2];
        c[0] = (f32x4){0.f, 0.f, 0.f, 0.f};
        c[1] = (f32x4){0.f, 0.f, 0.f, 0.f};
#pragma unroll
        for (int kk = 0; kk < 4; kk++) {
            const int co = ((kk * 4 + g) ^ (lr & 7)) * 8;
            bf8 a0h = *(const bf8*)(Q + lr * 128 + co);
            bf8 a0l = *(const bf8*)(Q + 4096 + lr * 128 + co);
            bf8 a1h = *(const bf8*)(Q + (16 + lr) * 128 + co);
            bf8 a1l = *(const bf8*)(Q + 4096 + (16 + lr) * 128 + co);
            c[0] = MFMA(a0h, bh[kk], c[0], 0, 0, 0);
            c[0] = MFMA(a0l, bh[kk], c[0], 0, 0, 0);
            c[0] = MFMA(a0h, bl[kk], c[0], 0, 0, 0);
            c[1] = MFMA(a1h, bh[kk], c[1], 0, 0, 0);
            c[1] = MFMA(a1l, bh[kk], c[1], 0, 0, 0);
            c[1] = MFMA(a1h, bl[kk], c[1], 0, 0, 0);
        }
        const float fa[4] = {f4a.x, f4a.y, f4a.z, f4a.w};
        const float fb[4] = {f4b.x, f4b.y, f4b.z, f4b.w};
        const int ksw = 2 * (lr & 3);
#pragma unroll
        for (int bt = 0; bt < 2; bt++) {
            us hh[4], ll[4];
#pragma unroll
            for (int r = 0; r < 4; r++) {
                float p = __expf(c[bt][r]) * (bt ? fb[r] : fa[r]);
                split2t(p, &hh[r], &ll[r]);
            }
            uint2 v;
            v.x = (unsigned)hh[0] | ((unsigned)hh[1] << 16);
            v.y = (unsigned)hh[2] | ((unsigned)hh[3] << 16);
            const int so = lr * PST + ((bt * 4 + g) ^ ksw) * 4;
            *(uint2*)(Ph + so) = v;
            v.x = (unsigned)ll[0] | ((unsigned)ll[1] << 16);
            v.y = (unsigned)ll[2] | ((unsigned)ll[3] << 16);
            *(uint2*)(Pl + so) = v;
        }
        const int ro = lr * PST + (g ^ (lr & 3)) * 8;
        bf8 pah = *(const bf8*)(Ph + ro);
        bf8 pal = *(const bf8*)(Pl + ro);
        SBAR();   // V(t) visible (each wave's VH drained by its ffac wait)
#pragma unroll
        for (int dt = 0; dt < 8; dt++) {
            bf8 vhh = *(const bf8*)(V + (dt * 16 + lr) * 32
                                      + ((g ^ ((lr >> 1) & 3)) * 8));
            acc[dt] = MFMA(pah, vhh, acc[dt], 0, 0, 0);
            acc[dt] = MFMA(pal, vhh, acc[dt], 0, 0, 0);
        }
        if (t + 1 < NT) {
            SBAR();   // PV reads of V done
            STAGE_VH(t + 1);
        }
        cur ^= 1;
    }
    // epilogue: new = memory + acc; L2-normalize; write memw_hi/lo + memwT_hi
    float n2[4] = {0.f, 0.f, 0.f, 0.f};
#pragma unroll
    for (int dt = 0; dt < 8; dt++)
#pragma unroll
        for (int r = 0; r < 4; r++) {
            float v = acc[dt][r]
                    + memory[(mrow + g * 4 + r) * H + dt * 16 + lr];
            acc[dt][r] = v;
            n2[r] += v * v;
        }
#pragma unroll
    for (int r = 0; r < 4; r++) {
#pragma unroll
        for (int x = 1; x < 16; x <<= 1) n2[r] += __shfl_xor(n2[r], x);
        n2[r] = 1.f / fmaxf(sqrtf(n2[r]), 1e-12f);
    }
#pragma unroll
    for (int dt = 0; dt < 8; dt++)
#pragma unroll
        for (int r = 0; r < 4; r++) {
            float vv = acc[dt][r] * n2[r];
            us h, lo2;
            split2t(vv, &h, &lo2);
            memw_hi[(mrow + g * 4 + r) * H + dt * 16 + lr] = h;
            memw_lo[(mrow + g * 4 + r) * H + dt * 16 + lr] = lo2;
        }
    __syncthreads();
#pragma unroll
    for (int dt = 0; dt < 8; dt++)
#pragma unroll
        for (int r = 0; r < 4; r++) {
            float vv = acc[dt][r] * n2[r];
            lds[(dt * 16 + lr) * 136 + w * 16 + g * 4 + r]
                = (us)(__float_as_uint(vv) >> 16);
        }
    __syncthreads();
    {
        const int d = tid >> 2, seg = tid & 3;   // 512 thr x 32 us = 128x128
        uint4* dq = (uint4*)(memwT_hi + (size_t)d * M + blockIdx.x * 128 + seg * 32);
        const uint4* sp = (const uint4*)(lds + d * 136 + seg * 32);
#pragma unroll
        for (int j = 0; j < 4; j++) dq[j] = sp[j];
    }
}

// ---------------- K7: flash read (8 waves x 16 b-rows) -----------------------
__global__ __launch_bounds__(512, 4) void k_fread(const us* __restrict__ memw_hi,
        const us* __restrict__ memw_lo, const us* __restrict__ memwT_hi,
        const us* __restrict__ qt_hi, const us* __restrict__ qt_lo,
        float* __restrict__ part, float* __restrict__ pmax2,
        float* __restrict__ psum2, int mchunk) {
    __shared__ us lds[29696];
    const int tid = threadIdx.x;
    const int w = tid >> 6, l = tid & 63;
    const int lr = l & 15, g = l >> 4;
    const int brow = blockIdx.x * 128 + w * 16;
    const int m0b = blockIdx.y * mchunk;
    const int rq = l >> 4, cq = l & 15;
    const int rv = l >> 2, cv = l & 3;
    bf8 qh[4], ql[4];
#pragma unroll
    for (int kk = 0; kk < 4; kk++) {
        const int o = (brow + lr) * H + kk * 32 + g * 8;
        qh[kk] = ldb(qt_hi + o);
        ql[kk] = ldb(qt_lo + o);
    }
    f32x4 acc[8];
#pragma unroll
    for (int dt = 0; dt < 8; dt++) acc[dt] = (f32x4){0.f, 0.f, 0.f, 0.f};
    float mb0 = 0.f, sm0 = 0.f;
    us* Ph = lds + 20480 + w * 1152;
    us* Pl = Ph + 576;
    auto STAGE_MW = [&](int t, int bi) {
        const int m0 = m0b + t * 32;
        us* Q = lds + bi * 8192;
#pragma unroll
        for (int i = 0; i < 2; i++) {
            const int id = w * 2 + i;
            const int ii = id & 7;
            const int r = ii * 4 + rq;
            const int cc = cq ^ (r & 7);
            gload16((id < 8 ? memw_hi : memw_lo) + (size_t)(m0 + r) * H + cc * 8,
                    Q + (id < 8 ? 0 : 4096) + ii * 512);
        }
    };
    auto STAGE_WT = [&](int t) {
        const int m0 = m0b + t * 32;
        us* V = lds + 16384;
        const int r = w * 16 + rv;
        const int cc = cv ^ ((rv >> 1) & 3);
        gload16(memwT_hi + (size_t)r * M + m0 + cc * 8, V + w * 512);
    };
    STAGE_MW(0, 0);
    STAGE_WT(0);
    int cur = 0;
    const int NT = mchunk / 32;
    const us* V = lds + 16384;
    for (int t = 0; t < NT; t++) {
        if (t + 1 < NT) { STAGE_MW(t + 1, cur ^ 1); SCHED_FENCE(); VMWAIT(3); }
        else { VMWAIT(1); }
        SBAR();   // memw tile t landed
        const us* Q = lds + cur * 8192;
        f32x4 c[2];
        c[0] = (f32x4){0.f, 0.f, 0.f, 0.f};
        c[1] = (f32x4){0.f, 0.f, 0.f, 0.f};
#pragma unroll
        for (int kk = 0; kk < 4; kk++) {
            const int co = ((kk * 4 + g) ^ (lr & 7)) * 8;
            bf8 a0h = *(const bf8*)(Q + lr * 128 + co);
            bf8 a0l = *(const bf8*)(Q + 4096 + lr * 128 + co);
            bf8 a1h = *(const bf8*)(Q + (16 + lr) * 128 + co);
            bf8 a1l = *(const bf8*)(Q + 4096 + (16 + lr) * 128 + co);
            c[0] = MFMA(a0h, qh[kk], c[0], 0, 0, 0);
            c[0] = MFMA(a0l, qh[kk], c[0], 0, 0, 0);
            c[0] = MFMA(a0h, ql[kk], c[0], 0, 0, 0);
            c[1] = MFMA(a1h, qh[kk], c[1], 0, 0, 0);
            c[1] = MFMA(a1l, qh[kk], c[1], 0, 0, 0);
            c[1] = MFMA(a1h, ql[kk], c[1], 0, 0, 0);
        }
        float s[2][4];
        float lmax = -INFINITY;
#pragma unroll
        for (int mt = 0; mt < 2; mt++)
#pragma unroll
            for (int r = 0; r < 4; r++) {
                s[mt][r] = c[mt][r] * SCALE2;
                lmax = fmaxf(lmax, s[mt][r]);
            }
        lmax = fmaxf(lmax, __shfl_xor(lmax, 16));
        lmax = fmaxf(lmax, __shfl_xor(lmax, 32));
        if (__any(lmax > mb0 + 8.f)) {
            float nm = fmaxf(mb0, lmax), f0 = __expf(mb0 - nm);
            sm0 *= f0;
            float fr[4];
#pragma unroll
            for (int r = 0; r < 4; r++) fr[r] = __shfl(f0, g * 4 + r);
#pragma unroll
            for (int dt = 0; dt < 8; dt++)
#pragma unroll
                for (int r = 0; r < 4; r++) acc[dt][r] *= fr[r];
            mb0 = nm;
        }
        const int ksw = 2 * (lr & 3);
#pragma unroll
        for (int mt = 0; mt < 2; mt++) {
            us hh[4], ll[4];
#pragma unroll
            for (int r = 0; r < 4; r++) {
                float p = __expf(s[mt][r] - mb0);
                sm0 += p;
                split2t(p, &hh[r], &ll[r]);
            }
            uint2 v;
            v.x = (unsigned)hh[0] | ((unsigned)hh[1] << 16);
            v.y = (unsigned)hh[2] | ((unsigned)hh[3] << 16);
            const int so = lr * PST + ((mt * 4 + g) ^ ksw) * 4;
            *(uint2*)(Ph + so) = v;
            v.x = (unsigned)ll[0] | ((unsigned)ll[1] << 16);
            v.y = (unsigned)ll[2] | ((unsigned)ll[3] << 16);
            *(uint2*)(Pl + so) = v;
        }
        const int ro = lr * PST + (g ^ (lr & 3)) * 8;
        bf8 pah = *(const bf8*)(Ph + ro);
        bf8 pal = *(const bf8*)(Pl + ro);
        if (t + 1 < NT) { VMWAIT(2); } else { VMWAIT(0); }
        SBAR();   // memwT tile t landed
#pragma unroll
        for (int dt = 0; dt < 8; dt++) {
            bf8 th = *(const bf8*)(V + (dt * 16 + lr) * 32
                                     + ((g ^ ((lr >> 1) & 3)) * 8));
            acc[dt] = MFMA(pah, th, acc[dt], 0, 0, 0);
            acc[dt] = MFMA(pal, th, acc[dt], 0, 0, 0);
        }
        if (t + 1 < NT) {
            SBAR();   // PV reads done
            STAGE_WT(t + 1);
        }
        cur ^= 1;
    }
    sm0 += __shfl_xor(sm0, 16);
    sm0 += __shfl_xor(sm0, 32);
    if (g == 0) {
        pmax2[(size_t)blockIdx.y * B + brow + lr] = mb0;
        psum2[(size_t)blockIdx.y * B + brow + lr] = sm0;
    }
    float* rp = part + (size_t)blockIdx.y * B * H;
#pragma unroll
    for (int dt = 0; dt < 8; dt++)
#pragma unroll
        for (int r = 0; r < 4; r++)
            rp[(size_t)(brow + g * 4 + r) * H + dt * 16 + lr] = acc[dt][r];
}

// ---------------- K8: per-b chunk weights ------------------------------------
__global__ __launch_bounds__(256) void k_fstats(const float* __restrict__ pmax2,
        const float* __restrict__ psum2, float* __restrict__ wc, int nc) {
    const int b = blockIdx.x * 256 + threadIdx.x;
    float gm = -INFINITY;
    for (int c = 0; c < nc; c++) gm = fmaxf(gm, pmax2[(size_t)c * B + b]);
    float z = 0.f;
    for (int c = 0; c < nc; c++)
        z += psum2[(size_t)c * B + b] * __expf(pmax2[(size_t)c * B + b] - gm);
    const float zi = 1.f / z;
    for (int c = 0; c < nc; c++)
        wc[(size_t)c * B + b] = __expf(pmax2[(size_t)c * B + b] - gm) * zi;
}

// ---------------- K9: weighted combine -> out --------------------------------
__global__ __launch_bounds__(256) void k_fcombine(const float* __restrict__ part,
        const float* __restrict__ wc, float* __restrict__ out, int nc) {
    const int i = blockIdx.x * 256 + threadIdx.x;
    const int b = i >> 7;
    float s = 0.f;
    for (int c = 0; c < nc; c++) s += part[(size_t)c * B * H + i] * wc[(size_t)c * B + b];
    out[i] = s;
}

extern "C" void kernel_launch(void* const* d_in, const int* in_sizes, int n_in,
                              void* d_out, int out_size, void* d_ws, size_t ws_size,
                              hipStream_t stream) {
    const float* ts     = (const float*)d_in[0];
    const float* inp    = (const float*)d_in[1];
    const float* memory = (const float*)d_in[2];
    const float* w_t    = (const float*)d_in[3];
    const float* b_t    = (const float*)d_in[4];
    const float* Wq     = (const float*)d_in[5];
    const float* Wk     = (const float*)d_in[6];
    const float* Wv     = (const float*)d_in[7];
    float* out = (float*)d_out;

    char* p = (char*)d_ws;
    auto alloc = [&](size_t bytes) { char* r = p; p += (bytes + 255) & ~(size_t)255; return r; };
    us* mem_hi   = (us*)alloc((size_t)M * H * 2);
    us* mem_lo   = (us*)alloc((size_t)M * H * 2);
    us* memw_hi  = (us*)alloc((size_t)M * H * 2);
    us* memw_lo  = (us*)alloc((size_t)M * H * 2);
    us* memwT_hi = (us*)alloc((size_t)M * H * 2);
    us* qt_hi    = (us*)alloc((size_t)B * H * 2);
    us* qt_lo    = (us*)alloc((size_t)B * H * 2);
    us* vhT_hi   = (us*)alloc((size_t)B * H * 2);
    float* vh    = (float*)alloc((size_t)B * H * 4);
    float* pmax  = (float*)alloc((size_t)B * SC * 4);
    float* psum  = (float*)alloc((size_t)B * SC * 4);
    float* ffac  = (float*)alloc((size_t)B * 4);
    size_t remain = ws_size - (size_t)(p - (char*)d_ws);
    int NC = 1;
    for (int c = 32; c >= 1; c >>= 1) {
        size_t need = (size_t)c * B * H * 4 + 3 * (size_t)c * B * 4 + 4096;
        if (need <= remain) { NC = c; break; }
    }
    float* pmax2 = (float*)alloc((size_t)NC * B * 4);
    float* psum2 = (float*)alloc((size_t)NC * B * 4);
    float* wcb   = (float*)alloc((size_t)NC * B * 4);
    float* part  = (float*)alloc((size_t)NC * B * H * 4);
    const int mchunk = M / NC;

    hipLaunchKernelGGL(k_prep, dim3(B), dim3(128), 0, stream,
                       ts, inp, w_t, b_t, Wq, Wk, Wv, qt_hi, qt_lo, vh);
    hipLaunchKernelGGL(k_splitmem, dim3(2048), dim3(256), 0, stream,
                       memory, mem_hi, mem_lo, M * H);
    hipLaunchKernelGGL(k_tx, dim3(H, B / 256), dim3(256), 0, stream, vh, vhT_hi);
    hipLaunchKernelGGL(k_stats, dim3(B / 128, SC), dim3(256), 0, stream,
                       mem_hi, mem_lo, qt_hi, qt_lo, M / SC, pmax, psum);
    hipLaunchKernelGGL(k_combine1, dim3(B / 256), dim3(256), 0, stream, pmax, psum, ffac);
    hipLaunchKernelGGL(k_update, dim3(M / 128), dim3(512), 0, stream,
                       memory, mem_hi, mem_lo, qt_hi, qt_lo, vhT_hi,
                       ffac, memw_hi, memw_lo, memwT_hi);
    hipLaunchKernelGGL(k_fread, dim3(B / 128, NC), dim3(512), 0, stream,
                       memw_hi, memw_lo, memwT_hi, qt_hi, qt_lo,
                       part, pmax2, psum2, mchunk);
    hipLaunchKernelGGL(k_fstats, dim3(B / 256), dim3(256), 0, stream, pmax2, psum2, wcb, NC);
    hipLaunchKernelGGL(k_fcombine, dim3(B * H / 256), dim3(256), 0, stream, part, wcb, out, NC);
}

// Round 12
// 528.591 us; speedup vs baseline: 1.7695x; 1.0859x over previous
//
#include <hip/hip_runtime.h>
#include <math.h>

#define B 2048
#define M 65536
#define H 128
#define TDIM 128
#define IDIM 256
#define SC 32            // stats-1 chunks over M
#define SCALE2 0.08838834764831845f
#define PST 32           // P-tile row stride (us): 64B rows, slot-XOR swizzled

typedef short bf8 __attribute__((ext_vector_type(8)));
typedef float f32x4 __attribute__((ext_vector_type(4)));
#define MFMA __builtin_amdgcn_mfma_f32_16x16x32_bf16
typedef unsigned short us;

#define SBAR() do { __builtin_amdgcn_sched_barrier(0); \
                    __builtin_amdgcn_s_barrier(); \
                    __builtin_amdgcn_sched_barrier(0); } while (0)
#define VMWAIT(N) do { asm volatile("s_waitcnt vmcnt(" #N ")" ::: "memory"); \
                       __builtin_amdgcn_sched_barrier(0); } while (0)
#define SCHED_FENCE() __builtin_amdgcn_sched_barrier(0)

__device__ inline us f2bf(float x) {
    unsigned u = __float_as_uint(x);
    u += 0x7FFF + ((u >> 16) & 1);
    return (us)(u >> 16);
}
__device__ inline float bf2f(us h) { return __uint_as_float(((unsigned)h) << 16); }
__device__ inline void split2(float x, us* hi, us* lo) {
    us h = f2bf(x); *hi = h; *lo = f2bf(x - bf2f(h));
}
__device__ inline void split2t(float x, us* hi, us* lo) {
    us h = (us)(__float_as_uint(x) >> 16);
    *hi = h; *lo = f2bf(x - bf2f(h));
}
__device__ inline bf8 ldb(const us* p) { return *(const bf8*)p; }
__device__ inline void gload16(const void* g, void* l) {
    __builtin_amdgcn_global_load_lds(
        (const __attribute__((address_space(1))) unsigned int*)g,
        (__attribute__((address_space(3))) unsigned int*)l, 16, 0, 0);
}

// ---------------- K1: prep: qt = ((cos-enc)@Wq^T)@Wk -> bf16 hi/lo; vh fp32 --
__global__ __launch_bounds__(128) void k_prep(const float* __restrict__ ts,
        const float* __restrict__ inp, const float* __restrict__ w_t,
        const float* __restrict__ b_t, const float* __restrict__ Wq,
        const float* __restrict__ Wk, const float* __restrict__ Wv,
        us* __restrict__ qt_hi, us* __restrict__ qt_lo, float* __restrict__ vh) {
    __shared__ float temb[TDIM];
    __shared__ float qh[H];
    const int b = blockIdx.x, t = threadIdx.x;
    temb[t] = cosf(ts[b] * w_t[t] + b_t[t]);
    __syncthreads();
    float s = 0.f;
    for (int k = 0; k < TDIM; k++) s += temb[k] * Wq[t * TDIM + k];
    qh[t] = s;
    __syncthreads();
    float s2 = 0.f;
    for (int j = 0; j < H; j++) s2 += qh[j] * Wk[j * H + t];
    us h, l;
    split2(s2, &h, &l);
    qt_hi[b * H + t] = h; qt_lo[b * H + t] = l;
    float s3 = 0.f;
    for (int i = 0; i < IDIM; i++) s3 += inp[b * IDIM + i] * Wv[t * IDIM + i];
    vh[b * H + t] = s3;
}

// ---------------- K2: split memory -> bf16 hi/lo -----------------------------
__global__ __launch_bounds__(256) void k_splitmem(const float* __restrict__ x,
        us* __restrict__ hi, us* __restrict__ lo, int n) {
    int i = blockIdx.x * 256 + threadIdx.x;
    const int stride = gridDim.x * 256;
    for (; i < n; i += stride) {
        us h, l;
        split2(x[i], &h, &l);
        hi[i] = h; lo[i] = l;
    }
}

// ---------------- K3: vh [B][H] -> vhT_hi [H][B] (hi only) -------------------
__global__ __launch_bounds__(256) void k_tx(const float* __restrict__ vh,
        us* __restrict__ vhT_hi) {
    const int d = blockIdx.x;
    const int b = blockIdx.y * 256 + threadIdx.x;
    vhT_hi[d * B + b] = f2bf(vh[b * H + d]);
}

// ---------------- K4: stats pass 1 (8 waves x 16 b-rows, triple-buf, 1 bar) --
__global__ __launch_bounds__(512, 4) void k_stats(const us* __restrict__ src_hi,
        const us* __restrict__ src_lo,
        const us* __restrict__ qt_hi, const us* __restrict__ qt_lo,
        int mchunk, float* __restrict__ pmax, float* __restrict__ psum) {
    __shared__ us lds[24576];   // 3 x 8192-us (hi 4096 | lo 4096) bufs
    const int tid = threadIdx.x;
    const int w = tid >> 6, l = tid & 63;
    const int lr = l & 15, g = l >> 4;
    const int brow = blockIdx.x * 128 + w * 16;
    const int m0b = blockIdx.y * mchunk;
    const int rq = l >> 4, cq = l & 15;
    bf8 qh[4], ql[4];
#pragma unroll
    for (int kk = 0; kk < 4; kk++) {
        const int o = (brow + lr) * H + kk * 32 + g * 8;
        qh[kk] = ldb(qt_hi + o);
        ql[kk] = ldb(qt_lo + o);
    }
    float mb[4], sm[4];
#pragma unroll
    for (int i = 0; i < 4; i++) { mb[i] = -INFINITY; sm[i] = 0.f; }
    auto STAGE = [&](int t, int bi) {
        const int m0 = m0b + t * 32;
        us* Q = lds + bi * 8192;
#pragma unroll
        for (int i = 0; i < 2; i++) {
            const int id = w * 2 + i;
            const int ii = id & 7;
            const int r = ii * 4 + rq;
            const int cc = cq ^ (r & 7);
            gload16((id < 8 ? src_hi : src_lo) + (size_t)(m0 + r) * H + cc * 8,
                    Q + (id < 8 ? 0 : 4096) + ii * 512);
        }
    };
    STAGE(0, 0);
    int qr = 0;
    const int NT = mchunk / 32;
    for (int t = 0; t < NT; t++) {
        const int nx = (qr == 2) ? 0 : qr + 1;
        if (t + 1 < NT) { STAGE(t + 1, nx); VMWAIT(2); }
        else { VMWAIT(0); }
        SBAR();   // tile t landed for all waves
        const us* Q = lds + qr * 8192;
        f32x4 c[2];
        c[0] = (f32x4){0.f, 0.f, 0.f, 0.f};
        c[1] = (f32x4){0.f, 0.f, 0.f, 0.f};
        __builtin_amdgcn_s_setprio(1);
#pragma unroll
        for (int kk = 0; kk < 4; kk++) {
            const int co = ((kk * 4 + g) ^ (lr & 7)) * 8;
            bf8 b0h = *(const bf8*)(Q + lr * 128 + co);
            bf8 b0l = *(const bf8*)(Q + 4096 + lr * 128 + co);
            bf8 b1h = *(const bf8*)(Q + (16 + lr) * 128 + co);
            bf8 b1l = *(const bf8*)(Q + 4096 + (16 + lr) * 128 + co);
            c[0] = MFMA(qh[kk], b0h, c[0], 0, 0, 0);
            c[0] = MFMA(ql[kk], b0h, c[0], 0, 0, 0);
            c[0] = MFMA(qh[kk], b0l, c[0], 0, 0, 0);
            c[1] = MFMA(qh[kk], b1h, c[1], 0, 0, 0);
            c[1] = MFMA(ql[kk], b1h, c[1], 0, 0, 0);
            c[1] = MFMA(qh[kk], b1l, c[1], 0, 0, 0);
        }
        __builtin_amdgcn_s_setprio(0);
        float dm = -INFINITY;
#pragma unroll
        for (int mt = 0; mt < 2; mt++)
#pragma unroll
            for (int r = 0; r < 4; r++)
                dm = fmaxf(dm, c[mt][r] - mb[r]);
        if (__any(dm > 8.f)) {
#pragma unroll
            for (int r = 0; r < 4; r++) {
                float mx = fmaxf(mb[r], fmaxf(c[0][r], c[1][r]));
                sm[r] = sm[r] * __expf(mb[r] - mx)
                      + __expf(c[0][r] - mx) + __expf(c[1][r] - mx);
                mb[r] = mx;
            }
        } else {
#pragma unroll
            for (int r = 0; r < 4; r++)
                sm[r] += __expf(c[0][r] - mb[r]) + __expf(c[1][r] - mb[r]);
        }
        qr = nx;
    }
#pragma unroll
    for (int r = 0; r < 4; r++) {
#pragma unroll
        for (int x = 1; x < 16; x <<= 1) {
            float om = __shfl_xor(mb[r], x);
            float os = __shfl_xor(sm[r], x);
            float nm = fmaxf(mb[r], om);
            sm[r] = sm[r] * __expf(mb[r] - nm) + os * __expf(om - nm);
            mb[r] = nm;
        }
    }
    if (lr == 0) {
#pragma unroll
        for (int r = 0; r < 4; r++) {
            const int row = brow + g * 4 + r;
            pmax[row * SC + blockIdx.y] = mb[r];
            psum[row * SC + blockIdx.y] = sm[r];
        }
    }
}

// ---------------- K5: combine -> ffac[b] = exp(-gmax)/Z ----------------------
__global__ __launch_bounds__(256) void k_combine1(const float* __restrict__ pmax,
        const float* __restrict__ psum, float* __restrict__ ffac) {
    const int b = blockIdx.x * 256 + threadIdx.x;
    float mx = -INFINITY;
    for (int c = 0; c < SC; c++) mx = fmaxf(mx, pmax[b * SC + c]);
    float z = 0.f;
    for (int c = 0; c < SC; c++) z += psum[b * SC + c] * __expf(pmax[b * SC + c] - mx);
    ffac[b] = __expf(-mx) / z;
}

// ---------------- K6: update (8 waves x 16 m-rows, 2 barriers/iter) ----------
// LDS (us): Q dbuf [0,16384) | V [16384,20480) | P [20480,28672).
// Top VMWAIT(4) drains BOTH Q(t) and V(t) -> no mid-iteration barrier needed.
__global__ __launch_bounds__(512, 4) void k_update(const float* __restrict__ memory,
        const us* __restrict__ mem_hi, const us* __restrict__ mem_lo,
        const us* __restrict__ qt_hi, const us* __restrict__ qt_lo,
        const us* __restrict__ vhT_hi, const float* __restrict__ ffac,
        us* __restrict__ memw_hi, us* __restrict__ memw_lo,
        us* __restrict__ memwT_hi) {
    __shared__ us lds[28672];
    const int tid = threadIdx.x;
    const int w = tid >> 6, l = tid & 63;
    const int lr = l & 15, g = l >> 4;
    const int mrow = blockIdx.x * 128 + w * 16;
    const int rq = l >> 4, cq = l & 15;
    const int rv = l >> 2, cv = l & 3;
    bf8 bh[4], bl[4];
#pragma unroll
    for (int kk = 0; kk < 4; kk++) {
        const int o = (mrow + lr) * H + kk * 32 + g * 8;
        bh[kk] = ldb(mem_hi + o);
        bl[kk] = ldb(mem_lo + o);
    }
    f32x4 acc[8];
#pragma unroll
    for (int dt = 0; dt < 8; dt++) acc[dt] = (f32x4){0.f, 0.f, 0.f, 0.f};
    us* Ph = lds + 20480 + w * 1024;
    us* Pl = Ph + 512;
    auto STAGE_QT = [&](int t, int bi) {
        const int b0 = t * 32;
        us* Q = lds + bi * 8192;
#pragma unroll
        for (int i = 0; i < 2; i++) {
            const int id = w * 2 + i;
            const int ii = id & 7;
            const int r = ii * 4 + rq;
            const int cc = cq ^ (r & 7);
            gload16((id < 8 ? qt_hi : qt_lo) + (size_t)(b0 + r) * H + cc * 8,
                    Q + (id < 8 ? 0 : 4096) + ii * 512);
        }
    };
    auto STAGE_VH = [&](int t) {
        const int b0 = t * 32;
        us* V = lds + 16384;
        const int r = w * 16 + rv;
        const int cc = cv ^ ((rv >> 1) & 3);
        gload16(vhT_hi + (size_t)r * B + b0 + cc * 8, V + w * 512);
    };
    STAGE_QT(0, 0);
    STAGE_VH(0);
    int cur = 0;
    const int NT = B / 32;
    const us* V = lds + 16384;
    for (int t = 0; t < NT; t++) {
        const int b0 = t * 32;
        const float4 f4a = *(const float4*)(ffac + b0 + g * 4);
        const float4 f4b = *(const float4*)(ffac + b0 + 16 + g * 4);
        SCHED_FENCE();
        if (t + 1 < NT) { STAGE_QT(t + 1, cur ^ 1); SCHED_FENCE(); VMWAIT(4); }
        else { VMWAIT(2); }
        SBAR();   // Q(t) AND V(t) landed for all waves
        const us* Q = lds + cur * 8192;
        f32x4 c[2];
        c[0] = (f32x4){0.f, 0.f, 0.f, 0.f};
        c[1] = (f32x4){0.f, 0.f, 0.f, 0.f};
        __builtin_amdgcn_s_setprio(1);
#pragma unroll
        for (int kk = 0; kk < 4; kk++) {
            const int co = ((kk * 4 + g) ^ (lr & 7)) * 8;
            bf8 a0h = *(const bf8*)(Q + lr * 128 + co);
            bf8 a0l = *(const bf8*)(Q + 4096 + lr * 128 + co);
            bf8 a1h = *(const bf8*)(Q + (16 + lr) * 128 + co);
            bf8 a1l = *(const bf8*)(Q + 4096 + (16 + lr) * 128 + co);
            c[0] = MFMA(a0h, bh[kk], c[0], 0, 0, 0);
            c[0] = MFMA(a0l, bh[kk], c[0], 0, 0, 0);
            c[0] = MFMA(a0h, bl[kk], c[0], 0, 0, 0);
            c[1] = MFMA(a1h, bh[kk], c[1], 0, 0, 0);
            c[1] = MFMA(a1l, bh[kk], c[1], 0, 0, 0);
            c[1] = MFMA(a1h, bl[kk], c[1], 0, 0, 0);
        }
        __builtin_amdgcn_s_setprio(0);
        const float fa[4] = {f4a.x, f4a.y, f4a.z, f4a.w};
        const float fb[4] = {f4b.x, f4b.y, f4b.z, f4b.w};
        const int ksw = 2 * (lr & 3);
#pragma unroll
        for (int bt = 0; bt < 2; bt++) {
            us hh[4], ll[4];
#pragma unroll
            for (int r = 0; r < 4; r++) {
                float p = __expf(c[bt][r]) * (bt ? fb[r] : fa[r]);
                split2t(p, &hh[r], &ll[r]);
            }
            uint2 v;
            v.x = (unsigned)hh[0] | ((unsigned)hh[1] << 16);
            v.y = (unsigned)hh[2] | ((unsigned)hh[3] << 16);
            const int so = lr * PST + ((bt * 4 + g) ^ ksw) * 4;
            *(uint2*)(Ph + so) = v;
            v.x = (unsigned)ll[0] | ((unsigned)ll[1] << 16);
            v.y = (unsigned)ll[2] | ((unsigned)ll[3] << 16);
            *(uint2*)(Pl + so) = v;
        }
        const int ro = lr * PST + (g ^ (lr & 3)) * 8;
        bf8 pah = *(const bf8*)(Ph + ro);
        bf8 pal = *(const bf8*)(Pl + ro);
        __builtin_amdgcn_s_setprio(1);
#pragma unroll
        for (int dt = 0; dt < 8; dt++) {
            bf8 vhh = *(const bf8*)(V + (dt * 16 + lr) * 32
                                      + ((g ^ ((lr >> 1) & 3)) * 8));
            acc[dt] = MFMA(pah, vhh, acc[dt], 0, 0, 0);
            acc[dt] = MFMA(pal, vhh, acc[dt], 0, 0, 0);
        }
        __builtin_amdgcn_s_setprio(0);
        if (t + 1 < NT) {
            SBAR();   // all PV reads of V(t) done; Q[cur] reads done
            STAGE_VH(t + 1);
        }
        cur ^= 1;
    }
    // epilogue: new = memory + acc; L2-normalize; write memw_hi/lo + memwT_hi
    float n2[4] = {0.f, 0.f, 0.f, 0.f};
#pragma unroll
    for (int dt = 0; dt < 8; dt++)
#pragma unroll
        for (int r = 0; r < 4; r++) {
            float v = acc[dt][r]
                    + memory[(mrow + g * 4 + r) * H + dt * 16 + lr];
            acc[dt][r] = v;
            n2[r] += v * v;
        }
#pragma unroll
    for (int r = 0; r < 4; r++) {
#pragma unroll
        for (int x = 1; x < 16; x <<= 1) n2[r] += __shfl_xor(n2[r], x);
        n2[r] = 1.f / fmaxf(sqrtf(n2[r]), 1e-12f);
    }
#pragma unroll
    for (int dt = 0; dt < 8; dt++)
#pragma unroll
        for (int r = 0; r < 4; r++) {
            float vv = acc[dt][r] * n2[r];
            us h, lo2;
            split2t(vv, &h, &lo2);
            memw_hi[(mrow + g * 4 + r) * H + dt * 16 + lr] = h;
            memw_lo[(mrow + g * 4 + r) * H + dt * 16 + lr] = lo2;
        }
    __syncthreads();
#pragma unroll
    for (int dt = 0; dt < 8; dt++)
#pragma unroll
        for (int r = 0; r < 4; r++) {
            float vv = acc[dt][r] * n2[r];
            lds[(dt * 16 + lr) * 136 + w * 16 + g * 4 + r]
                = (us)(__float_as_uint(vv) >> 16);
        }
    __syncthreads();
    {
        const int d = tid >> 2, seg = tid & 3;   // 512 thr x 32 us = 128x128
        uint4* dq = (uint4*)(memwT_hi + (size_t)d * M + blockIdx.x * 128 + seg * 32);
        const uint4* sp = (const uint4*)(lds + d * 136 + seg * 32);
#pragma unroll
        for (int j = 0; j < 4; j++) dq[j] = sp[j];
    }
}

// ---------------- K7: flash read (8 waves x 16 b-rows, 2 barriers/iter) ------
__global__ __launch_bounds__(512, 4) void k_fread(const us* __restrict__ memw_hi,
        const us* __restrict__ memw_lo, const us* __restrict__ memwT_hi,
        const us* __restrict__ qt_hi, const us* __restrict__ qt_lo,
        float* __restrict__ part, float* __restrict__ pmax2,
        float* __restrict__ psum2, int mchunk) {
    __shared__ us lds[28672];
    const int tid = threadIdx.x;
    const int w = tid >> 6, l = tid & 63;
    const int lr = l & 15, g = l >> 4;
    const int brow = blockIdx.x * 128 + w * 16;
    const int m0b = blockIdx.y * mchunk;
    const int rq = l >> 4, cq = l & 15;
    const int rv = l >> 2, cv = l & 3;
    bf8 qh[4], ql[4];
#pragma unroll
    for (int kk = 0; kk < 4; kk++) {
        const int o = (brow + lr) * H + kk * 32 + g * 8;
        qh[kk] = ldb(qt_hi + o);
        ql[kk] = ldb(qt_lo + o);
    }
    f32x4 acc[8];
#pragma unroll
    for (int dt = 0; dt < 8; dt++) acc[dt] = (f32x4){0.f, 0.f, 0.f, 0.f};
    float mb0 = 0.f, sm0 = 0.f;
    us* Ph = lds + 20480 + w * 1024;
    us* Pl = Ph + 512;
    auto STAGE_MW = [&](int t, int bi) {
        const int m0 = m0b + t * 32;
        us* Q = lds + bi * 8192;
#pragma unroll
        for (int i = 0; i < 2; i++) {
            const int id = w * 2 + i;
            const int ii = id & 7;
            const int r = ii * 4 + rq;
            const int cc = cq ^ (r & 7);
            gload16((id < 8 ? memw_hi : memw_lo) + (size_t)(m0 + r) * H + cc * 8,
                    Q + (id < 8 ? 0 : 4096) + ii * 512);
        }
    };
    auto STAGE_WT = [&](int t) {
        const int m0 = m0b + t * 32;
        us* V = lds + 16384;
        const int r = w * 16 + rv;
        const int cc = cv ^ ((rv >> 1) & 3);
        gload16(memwT_hi + (size_t)r * M + m0 + cc * 8, V + w * 512);
    };
    STAGE_MW(0, 0);
    STAGE_WT(0);
    int cur = 0;
    const int NT = mchunk / 32;
    const us* V = lds + 16384;
    for (int t = 0; t < NT; t++) {
        if (t + 1 < NT) { STAGE_MW(t + 1, cur ^ 1); SCHED_FENCE(); VMWAIT(2); }
        else { VMWAIT(0); }
        SBAR();   // memw(t) AND memwT(t) landed
        const us* Q = lds + cur * 8192;
        f32x4 c[2];
        c[0] = (f32x4){0.f, 0.f, 0.f, 0.f};
        c[1] = (f32x4){0.f, 0.f, 0.f, 0.f};
        __builtin_amdgcn_s_setprio(1);
#pragma unroll
        for (int kk = 0; kk < 4; kk++) {
            const int co = ((kk * 4 + g) ^ (lr & 7)) * 8;
            bf8 a0h = *(const bf8*)(Q + lr * 128 + co);
            bf8 a0l = *(const bf8*)(Q + 4096 + lr * 128 + co);
            bf8 a1h = *(const bf8*)(Q + (16 + lr) * 128 + co);
            bf8 a1l = *(const bf8*)(Q + 4096 + (16 + lr) * 128 + co);
            c[0] = MFMA(a0h, qh[kk], c[0], 0, 0, 0);
            c[0] = MFMA(a0l, qh[kk], c[0], 0, 0, 0);
            c[0] = MFMA(a0h, ql[kk], c[0], 0, 0, 0);
            c[1] = MFMA(a1h, qh[kk], c[1], 0, 0, 0);
            c[1] = MFMA(a1l, qh[kk], c[1], 0, 0, 0);
            c[1] = MFMA(a1h, ql[kk], c[1], 0, 0, 0);
        }
        __builtin_amdgcn_s_setprio(0);
        float s[2][4];
        float lmax = -INFINITY;
#pragma unroll
        for (int mt = 0; mt < 2; mt++)
#pragma unroll
            for (int r = 0; r < 4; r++) {
                s[mt][r] = c[mt][r] * SCALE2;
                lmax = fmaxf(lmax, s[mt][r]);
            }
        lmax = fmaxf(lmax, __shfl_xor(lmax, 16));
        lmax = fmaxf(lmax, __shfl_xor(lmax, 32));
        if (__any(lmax > mb0 + 8.f)) {
            float nm = fmaxf(mb0, lmax), f0 = __expf(mb0 - nm);
            sm0 *= f0;
            float fr[4];
#pragma unroll
            for (int r = 0; r < 4; r++) fr[r] = __shfl(f0, g * 4 + r);
#pragma unroll
            for (int dt = 0; dt < 8; dt++)
#pragma unroll
                for (int r = 0; r < 4; r++) acc[dt][r] *= fr[r];
            mb0 = nm;
        }
        const int ksw = 2 * (lr & 3);
#pragma unroll
        for (int mt = 0; mt < 2; mt++) {
            us hh[4], ll[4];
#pragma unroll
            for (int r = 0; r < 4; r++) {
                float p = __expf(s[mt][r] - mb0);
                sm0 += p;
                split2t(p, &hh[r], &ll[r]);
            }
            uint2 v;
            v.x = (unsigned)hh[0] | ((unsigned)hh[1] << 16);
            v.y = (unsigned)hh[2] | ((unsigned)hh[3] << 16);
            const int so = lr * PST + ((mt * 4 + g) ^ ksw) * 4;
            *(uint2*)(Ph + so) = v;
            v.x = (unsigned)ll[0] | ((unsigned)ll[1] << 16);
            v.y = (unsigned)ll[2] | ((unsigned)ll[3] << 16);
            *(uint2*)(Pl + so) = v;
        }
        const int ro = lr * PST + (g ^ (lr & 3)) * 8;
        bf8 pah = *(const bf8*)(Ph + ro);
        bf8 pal = *(const bf8*)(Pl + ro);
        __builtin_amdgcn_s_setprio(1);
#pragma unroll
        for (int dt = 0; dt < 8; dt++) {
            bf8 th = *(const bf8*)(V + (dt * 16 + lr) * 32
                                     + ((g ^ ((lr >> 1) & 3)) * 8));
            acc[dt] = MFMA(pah, th, acc[dt], 0, 0, 0);
            acc[dt] = MFMA(pal, th, acc[dt], 0, 0, 0);
        }
        __builtin_amdgcn_s_setprio(0);
        if (t + 1 < NT) {
            SBAR();   // PV reads of WT(t) done
            STAGE_WT(t + 1);
        }
        cur ^= 1;
    }
    sm0 += __shfl_xor(sm0, 16);
    sm0 += __shfl_xor(sm0, 32);
    if (g == 0) {
        pmax2[(size_t)blockIdx.y * B + brow + lr] = mb0;
        psum2[(size_t)blockIdx.y * B + brow + lr] = sm0;
    }
    float* rp = part + (size_t)blockIdx.y * B * H;
#pragma unroll
    for (int dt = 0; dt < 8; dt++)
#pragma unroll
        for (int r = 0; r < 4; r++)
            rp[(size_t)(brow + g * 4 + r) * H + dt * 16 + lr] = acc[dt][r];
}

// ---------------- K8: per-b chunk weights ------------------------------------
__global__ __launch_bounds__(256) void k_fstats(const float* __restrict__ pmax2,
        const float* __restrict__ psum2, float* __restrict__ wc, int nc) {
    const int b = blockIdx.x * 256 + threadIdx.x;
    float gm = -INFINITY;
    for (int c = 0; c < nc; c++) gm = fmaxf(gm, pmax2[(size_t)c * B + b]);
    float z = 0.f;
    for (int c = 0; c < nc; c++)
        z += psum2[(size_t)c * B + b] * __expf(pmax2[(size_t)c * B + b] - gm);
    const float zi = 1.f / z;
    for (int c = 0; c < nc; c++)
        wc[(size_t)c * B + b] = __expf(pmax2[(size_t)c * B + b] - gm) * zi;
}

// ---------------- K9: weighted combine -> out --------------------------------
__global__ __launch_bounds__(256) void k_fcombine(const float* __restrict__ part,
        const float* __restrict__ wc, float* __restrict__ out, int nc) {
    const int i = blockIdx.x * 256 + threadIdx.x;
    const int b = i >> 7;
    float s = 0.f;
    for (int c = 0; c < nc; c++) s += part[(size_t)c * B * H + i] * wc[(size_t)c * B + b];
    out[i] = s;
}

extern "C" void kernel_launch(void* const* d_in, const int* in_sizes, int n_in,
                              void* d_out, int out_size, void* d_ws, size_t ws_size,
                              hipStream_t stream) {
    const float* ts     = (const float*)d_in[0];
    const float* inp    = (const float*)d_in[1];
    const float* memory = (const float*)d_in[2];
    const float* w_t    = (const float*)d_in[3];
    const float* b_t    = (const float*)d_in[4];
    const float* Wq     = (const float*)d_in[5];
    const float* Wk     = (const float*)d_in[6];
    const float* Wv     = (const float*)d_in[7];
    float* out = (float*)d_out;

    char* p = (char*)d_ws;
    auto alloc = [&](size_t bytes) { char* r = p; p += (bytes + 255) & ~(size_t)255; return r; };
    us* mem_hi   = (us*)alloc((size_t)M * H * 2);
    us* mem_lo   = (us*)alloc((size_t)M * H * 2);
    us* memw_hi  = (us*)alloc((size_t)M * H * 2);
    us* memw_lo  = (us*)alloc((size_t)M * H * 2);
    us* memwT_hi = (us*)alloc((size_t)M * H * 2);
    us* qt_hi    = (us*)alloc((size_t)B * H * 2);
    us* qt_lo    = (us*)alloc((size_t)B * H * 2);
    us* vhT_hi   = (us*)alloc((size_t)B * H * 2);
    float* vh    = (float*)alloc((size_t)B * H * 4);
    float* pmax  = (float*)alloc((size_t)B * SC * 4);
    float* psum  = (float*)alloc((size_t)B * SC * 4);
    float* ffac  = (float*)alloc((size_t)B * 4);
    size_t remain = ws_size - (size_t)(p - (char*)d_ws);
    int NC = 1;
    for (int c = 32; c >= 1; c >>= 1) {
        size_t need = (size_t)c * B * H * 4 + 3 * (size_t)c * B * 4 + 4096;
        if (need <= remain) { NC = c; break; }
    }
    float* pmax2 = (float*)alloc((size_t)NC * B * 4);
    float* psum2 = (float*)alloc((size_t)NC * B * 4);
    float* wcb   = (float*)alloc((size_t)NC * B * 4);
    float* part  = (float*)alloc((size_t)NC * B * H * 4);
    const int mchunk = M / NC;

    hipLaunchKernelGGL(k_prep, dim3(B), dim3(128), 0, stream,
                       ts, inp, w_t, b_t, Wq, Wk, Wv, qt_hi, qt_lo, vh);
    hipLaunchKernelGGL(k_splitmem, dim3(2048), dim3(256), 0, stream,
                       memory, mem_hi, mem_lo, M * H);
    hipLaunchKernelGGL(k_tx, dim3(H, B / 256), dim3(256), 0, stream, vh, vhT_hi);
    hipLaunchKernelGGL(k_stats, dim3(B / 128, SC), dim3(512), 0, stream,
                       mem_hi, mem_lo, qt_hi, qt_lo, M / SC, pmax, psum);
    hipLaunchKernelGGL(k_combine1, dim3(B / 256), dim3(256), 0, stream, pmax, psum, ffac);
    hipLaunchKernelGGL(k_update, dim3(M / 128), dim3(512), 0, stream,
                       memory, mem_hi, mem_lo, qt_hi, qt_lo, vhT_hi,
                       ffac, memw_hi, memw_lo, memwT_hi);
    hipLaunchKernelGGL(k_fread, dim3(B / 128, NC), dim3(512), 0, stream,
                       memw_hi, memw_lo, memwT_hi, qt_hi, qt_lo,
                       part, pmax2, psum2, mchunk);
    hipLaunchKernelGGL(k_fstats, dim3(B / 256), dim3(256), 0, stream, pmax2, psum2, wcb, NC);
    hipLaunchKernelGGL(k_fcombine, dim3(B * H / 256), dim3(256), 0, stream, part, wcb, out, NC);
}